// Round 11
// baseline (310.885 us; speedup 1.0000x reference)
//
#include <hip/hip_runtime.h>
#include <math.h>

// Problem constants
// x: (16,64,3,32,32) x2 concat -> (1024,6,32,32)
// conv1 6->64 k3 p1 -> BN -> ReLU -> pool2 -> (1024,64,16,16)
// conv2 64->64 k3 p1 -> BN -> ReLU -> pool2 -> (1024,64,8,8) = feats (1024,4096)
// RNN T=64 steps over feats rows n=b*64+t ; head -> sigmoid (16,1)

typedef __attribute__((ext_vector_type(8))) short s8v;   // 8 bf16 (4 VGPRs)
typedef __attribute__((ext_vector_type(4))) float f32x4;

__device__ __forceinline__ unsigned short f2bf(float f) {
  union { float f; unsigned u; } x; x.f = f;
  return (unsigned short)((x.u + 0x7FFFu + ((x.u >> 16) & 1u)) >> 16);  // RNE
}
__device__ __forceinline__ float bf2f(unsigned short u) {
  union { unsigned u; float f; } x; x.u = ((unsigned)u) << 16; return x.f;
}
// fast tanh: 1 - 2/(e^{2x}+1); inf-safe via rcp (e=inf -> 0 -> +1; e->0 -> -1)
__device__ __forceinline__ float ftanh(float x) {
  float e = __expf(2.f * x);
  return 1.f - 2.f * __builtin_amdgcn_rcpf(e + 1.f);
}

// ---------------------------------------------------------------------------
// w1 pack: fp32 [co][ci=6][kh][kw] -> bf16 [kh][64co][32k], k = kw*6+ci,
// ZEROS at k in [18,32) -- these multiply the A-side overread garbage.
// ---------------------------------------------------------------------------
__global__ __launch_bounds__(256)
void w1_pack(const float* __restrict__ w1, unsigned short* __restrict__ wB1)
{
  int i = blockIdx.x*256 + threadIdx.x;   // 3*64*32 = 6144
  if (i < 6144) {
    int kh = i >> 11, rem = i & 2047, co = rem >> 5, k2 = rem & 31;
    unsigned short v = 0;
    if (k2 < 18) {
      int kw = k2 / 6, ci = k2 - 6*kw;
      v = f2bf(w1[co*54 + ci*9 + kh*3 + kw]);
    }
    wB1[i] = v;
  }
}

// ---------------------------------------------------------------------------
// conv1 via MFMA implicit GEMM, computed ONCE. grid 1024, block 256 (4 waves).
// Epilogue: per-channel sum/sumsq + 2x2 pooled max/min bf16 channel-last.
// ---------------------------------------------------------------------------
__global__ __launch_bounds__(256, 4)
void conv1_mfma(const float* __restrict__ x1, const float* __restrict__ x2,
                const unsigned short* __restrict__ wB1,
                float* __restrict__ part,
                unsigned short* __restrict__ pmax1, unsigned short* __restrict__ pmin1)
{
  __shared__ unsigned xin[3688];          // 34 rows x 108 dwords + 16 pad
  __shared__ float wred[4][4][16][2];
  const int n = blockIdx.x, tid = threadIdx.x;
  const int w = tid >> 6, lane = tid & 63;
  const int q = lane >> 4, r = lane & 15;

  // B fragments, whole kernel in regs: bf[kh][t], co = 16t + r, k0 = 8q
  s8v bf[3][4];
  #pragma unroll
  for (int kh = 0; kh < 3; ++kh)
    #pragma unroll
    for (int t = 0; t < 4; ++t)
      bf[kh][t] = *(const s8v*)&wB1[kh*2048 + (((t<<4)+r)<<5) + (q<<3)];

  // zero ALL of xin (incl. pad tail) -- overread garbage must be finite
  #pragma unroll
  for (int k = 0; k < 15; ++k) {
    int i = tid + (k<<8);
    if (i < 3688) xin[i] = 0;
  }
  __syncthreads();
  // interior fill: dword (y+1)*108 + (x+1)*3 + cp packs bf16{ci=2cp,2cp+1}
  #pragma unroll
  for (int k = 0; k < 12; ++k) {
    int i = tid + (k<<8);     // 0..3071
    int cp = i >> 10, p = i & 1023;
    int y = p >> 5, x = p & 31;
    float lo, hi;
    if (cp == 0)      { lo = x1[n*3072 + p];        hi = x1[n*3072 + 1024 + p]; }
    else if (cp == 1) { lo = x1[n*3072 + 2048 + p]; hi = x2[n*3072 + p];        }
    else              { lo = x2[n*3072 + 1024 + p]; hi = x2[n*3072 + 2048 + p]; }
    xin[(y+1)*108 + (x+1)*3 + cp] = (unsigned)f2bf(lo) | ((unsigned)f2bf(hi) << 16);
  }
  __syncthreads();

  float st[4], sq[4];
  #pragma unroll
  for (int t = 0; t < 4; ++t) { st[t] = 0.f; sq[t] = 0.f; }
  float pmx[4][2], pmn[4][2];

  #pragma unroll 1
  for (int xb = 0; xb < 2; ++xb) {
    const int xbase = xb << 4;
    #pragma unroll 2
    for (int j = 0; j < 8; ++j) {           // y = 8w + j
      const int y = (w << 3) + j;
      f32x4 acc[4];
      #pragma unroll
      for (int t = 0; t < 4; ++t) acc[t] = (f32x4){0.f,0.f,0.f,0.f};
      #pragma unroll
      for (int kh = 0; kh < 3; ++kh) {      // k-step == kh slice
        int dw = (y + kh)*108 + 3*(xbase + r) + (q << 2);
        union { unsigned u[4]; s8v v; } af;
        af.u[0] = xin[dw];   af.u[1] = xin[dw+1];
        af.u[2] = xin[dw+2]; af.u[3] = xin[dw+3];
        #pragma unroll
        for (int t = 0; t < 4; ++t)
          acc[t] = __builtin_amdgcn_mfma_f32_16x16x32_bf16(af.v, bf[kh][t], acc[t], 0, 0, 0);
      }
      #pragma unroll
      for (int t = 0; t < 4; ++t) {
        st[t] += acc[t][0]+acc[t][1]+acc[t][2]+acc[t][3];
        sq[t] = fmaf(acc[t][0],acc[t][0], fmaf(acc[t][1],acc[t][1],
                fmaf(acc[t][2],acc[t][2], fmaf(acc[t][3],acc[t][3], sq[t]))));
      }
      if ((j & 1) == 0) {                   // even y: stash x-pair max/min
        #pragma unroll
        for (int t = 0; t < 4; ++t) {
          pmx[t][0] = fmaxf(acc[t][0], acc[t][1]); pmx[t][1] = fmaxf(acc[t][2], acc[t][3]);
          pmn[t][0] = fminf(acc[t][0], acc[t][1]); pmn[t][1] = fminf(acc[t][2], acc[t][3]);
        }
      } else {                              // odd y: combine + write pooled
        const int py = y >> 1;
        #pragma unroll
        for (int t = 0; t < 4; ++t) {
          int co = (t << 4) + r;
          #pragma unroll
          for (int pp = 0; pp < 2; ++pp) {
            float mx = fmaxf(pmx[t][pp], fmaxf(acc[t][2*pp], acc[t][2*pp+1]));
            float mn = fminf(pmn[t][pp], fminf(acc[t][2*pp], acc[t][2*pp+1]));
            int pxp = (xb << 3) + (q << 1) + pp;
            int o = (((n << 8) + (py << 4) + pxp) << 6) + co;
            pmax1[o] = f2bf(mx);
            pmin1[o] = f2bf(mn);
          }
        }
      }
    }
  }

  #pragma unroll
  for (int t = 0; t < 4; ++t) {
    float s = st[t], ss = sq[t];
    s  += __shfl_xor(s, 16);  s  += __shfl_xor(s, 32);
    ss += __shfl_xor(ss, 16); ss += __shfl_xor(ss, 32);
    if (q == 0) { wred[w][t][r][0] = s; wred[w][t][r][1] = ss; }
  }
  __syncthreads();
  if (tid < 64) {
    float s = 0.f, ss = 0.f;
    #pragma unroll
    for (int wv = 0; wv < 4; ++wv) {
      s  += wred[wv][tid >> 4][tid & 15][0];
      ss += wred[wv][tid >> 4][tid & 15][1];
    }
    part[tid*2048 + n*2]     = s;     // layout [c][n][2]
    part[tid*2048 + n*2 + 1] = ss;
  }
}

// ---------------------------------------------------------------------------
// BN finalize: per-channel mean/var -> scale/shift.  grid 64, block 256.
// ---------------------------------------------------------------------------
__global__ __launch_bounds__(256)
void bn_finalize(const float* __restrict__ part, const float* __restrict__ g,
                 const float* __restrict__ beta, float inv_cnt, float* __restrict__ bn)
{
  __shared__ float red[8];
  const int c = blockIdx.x, tid = threadIdx.x;
  float s = 0.f, ss = 0.f;
  for (int n = tid; n < 1024; n += 256) {
    s  += part[c*2048 + n*2];
    ss += part[c*2048 + n*2 + 1];
  }
  #pragma unroll
  for (int d = 32; d; d >>= 1) { s += __shfl_xor(s, d); ss += __shfl_xor(ss, d); }
  if ((tid & 63) == 0) { red[(tid>>6)*2] = s; red[(tid>>6)*2+1] = ss; }
  __syncthreads();
  if (tid == 0) {
    float S  = red[0]+red[2]+red[4]+red[6];
    float SS = red[1]+red[3]+red[5]+red[7];
    float m  = S * inv_cnt;
    float var = SS * inv_cnt - m*m;
    float sc = g[c] * rsqrtf(var + 1e-5f);
    bn[c]    = sc;
    bn[64+c] = beta[c] - m*sc;
  }
}

// ---------------------------------------------------------------------------
// w2 pack: fp32 [co][ci][kh][kw] -> bf16 [khw][co][ci] with the ci-chunk
// XOR-swizzle ((ci>>3)^(co&7)) pre-applied so conv2's LDS copy is linear.
// ---------------------------------------------------------------------------
__global__ __launch_bounds__(256)
void w2_pack(const float* __restrict__ w2, unsigned short* __restrict__ wB)
{
  int i = blockIdx.x*256 + threadIdx.x;   // 9*64*64 = 36864
  if (i < 36864) {
    int khw = i >> 12, rem = i & 4095, co = rem >> 6, ci = rem & 63;
    int chunk = (ci >> 3) ^ (co & 7);
    wB[khw*4096 + co*64 + chunk*8 + (ci & 7)] = f2bf(w2[co*576 + ci*9 + khw]);
  }
}

// ---------------------------------------------------------------------------
// Qw pack: fp32 [100][4196] (first 4096 cols) -> bf16 [112][4096],
// rows 100..111 zeroed (N padded to 7x16 MFMA tiles).
// ---------------------------------------------------------------------------
__global__ __launch_bounds__(256)
void qw_pack(const float* __restrict__ Qw, unsigned short* __restrict__ qB)
{
  int i = blockIdx.x*256 + threadIdx.x;   // 112*4096 = 458752
  if (i < 458752) {
    int j = i >> 12, k = i & 4095;
    qB[i] = (j < 100) ? f2bf(Qw[j*4196 + k]) : (unsigned short)0;
  }
}

// ---------------------------------------------------------------------------
// RNN weight pack (R11, za-reformulation):
//  gB bf16 [512 p][128 k]: G[p=4*o'+a][k=o] = Rw[o'][a*100+o]; zero padded.
//  qrB bf16 [128 o][128 kr]: Qw recurrent cols, zero padded.
// ---------------------------------------------------------------------------
__global__ __launch_bounds__(256)
void rq_pack(const float* __restrict__ Rw, const float* __restrict__ Qw,
             unsigned short* __restrict__ gB, unsigned short* __restrict__ qrB)
{
  int i = blockIdx.x*256 + threadIdx.x;   // 65536 + 16384 = 81920
  if (i < 65536) {
    int p = i >> 7, k = i & 127;
    unsigned short v = 0;
    if (p < 400 && k < 100) v = f2bf(Rw[(p >> 2)*400 + (p & 3)*100 + k]);
    gB[i] = v;
  } else if (i < 81920) {
    int j = i - 65536;
    int o = j >> 7, kr = j & 127;
    qrB[j] = (o < 100 && kr < 100) ? f2bf(Qw[o*4196 + 4096 + kr]) : (unsigned short)0;
  }
}

// ---------------------------------------------------------------------------
// conv2 via MFMA implicit GEMM. grid 1024 (one image), block 256 (4 waves).
// Staging FUSES conv1's BN affine + ReLU. Pooled raw outputs stored bf16.
// ---------------------------------------------------------------------------
__global__ __launch_bounds__(256)
void conv2_mfma(const unsigned short* __restrict__ pmax1,
                const unsigned short* __restrict__ pmin1,
                const float* __restrict__ bn1,
                const unsigned short* __restrict__ wB,
                float* __restrict__ part,
                unsigned short* __restrict__ pmax2, unsigned short* __restrict__ pmin2)
{
  __shared__ unsigned short xin[324*64];   // 41472 B
  __shared__ unsigned short wL[9*64*64];   // 73728 B
  __shared__ float wred[4][4][16][2];      // 2 KB
  __shared__ float bnL[128];
  const int n = blockIdx.x, tid = threadIdx.x;
  const int w = tid >> 6, lane = tid & 63;
  const int q = lane >> 4, col = lane & 15;

  if (tid < 128) bnL[tid] = bn1[tid];
  // ---- stage weights (linear copy; swizzle pre-applied by w2_pack) ----
  {
    const s8v* src = (const s8v*)wB;
    s8v* dst = (s8v*)wL;
    #pragma unroll
    for (int i = 0; i < 18; ++i) dst[tid + (i<<8)] = src[tid + (i<<8)];
  }
  __syncthreads();   // bnL ready
  // ---- stage input 18x18x64 bf16 = relu(affine(pooled conv1)), halo zeros,
  //      swizzled 16B chunks ----
  {
    #pragma unroll
    for (int k = 0; k < 11; ++k) {
      int i = tid + (k<<8);
      if (i < 324*8) {
        int L = i >> 3, s = i & 7;
        int y = L / 18, x = L - y*18;
        s8v v = (s8v){0,0,0,0,0,0,0,0};
        if (y >= 1 && y <= 16 && x >= 1 && x <= 16) {
          int idx = (((n<<8) + ((y-1)<<4) + (x-1))<<6) + (s<<3);
          s8v mx = *(const s8v*)&pmax1[idx];
          s8v mn = *(const s8v*)&pmin1[idx];
          #pragma unroll
          for (int e = 0; e < 8; ++e) {
            int ci = (s<<3) + e;
            float sc = bnL[ci], sh = bnL[64+ci];
            float vv = bf2f((unsigned short)(sc >= 0.f ? mx[e] : mn[e]));
            v[e] = (short)f2bf(fmaxf(fmaf(vv, sc, sh), 0.f));
          }
        }
        *(s8v*)((char*)xin + L*128 + (((s ^ (L & 7)) << 4))) = v;
      }
    }
  }
  __syncthreads();

  f32x4 acc[4][4];   // [mtile][ntile]
  #pragma unroll
  for (int mt = 0; mt < 4; ++mt)
    #pragma unroll
    for (int t = 0; t < 4; ++t)
      acc[mt][t] = (f32x4){0.f,0.f,0.f,0.f};

  const int py0 = w << 2;   // wave's 4 image rows
  #pragma unroll 1
  for (int khw = 0; khw < 9; ++khw) {
    const int kh = khw / 3, kw = khw - 3*kh;
    const char* wslice = (const char*)wL + khw*8192;
    #pragma unroll
    for (int ks = 0; ks < 2; ++ks) {       // ci0 = 32*ks
      const int chunk = (ks << 2) + q;     // 16B-chunk of k within line
      s8v bfrag[4];
      #pragma unroll
      for (int t = 0; t < 4; ++t) {
        int co = (t << 4) + col;
        bfrag[t] = *(const s8v*)(wslice + co*128 + (((chunk ^ (co & 7)) << 4)));
      }
      #pragma unroll
      for (int mt = 0; mt < 4; ++mt) {
        int L = (py0 + mt + kh)*18 + (col + kw);
        s8v afrag = *(const s8v*)((const char*)xin + L*128 + (((chunk ^ (L & 7)) << 4)));
        #pragma unroll
        for (int t = 0; t < 4; ++t)
          acc[mt][t] = __builtin_amdgcn_mfma_f32_16x16x32_bf16(afrag, bfrag[t], acc[mt][t], 0, 0, 0);
      }
    }
  }

  // ---- stats: per-channel sum / sumsq over this block's 256 pixels ----
  #pragma unroll
  for (int t = 0; t < 4; ++t) {
    float s = 0.f, ss = 0.f;
    #pragma unroll
    for (int mt = 0; mt < 4; ++mt)
      #pragma unroll
      for (int r = 0; r < 4; ++r) {
        float v = acc[mt][t][r];
        s += v; ss = fmaf(v, v, ss);
      }
    s  += __shfl_xor(s, 16);  s  += __shfl_xor(s, 32);
    ss += __shfl_xor(ss, 16); ss += __shfl_xor(ss, 32);
    if (q == 0) { wred[w][t][col][0] = s; wred[w][t][col][1] = ss; }
  }
  __syncthreads();
  if (tid < 64) {
    float s = 0.f, ss = 0.f;
    #pragma unroll
    for (int wv = 0; wv < 4; ++wv) {
      s  += wred[wv][tid >> 4][tid & 15][0];
      ss += wred[wv][tid >> 4][tid & 15][1];
    }
    part[tid*2048 + n*2]     = s;
    part[tid*2048 + n*2 + 1] = ss;
  }

  // ---- 2x2 pooled max AND min of raw conv (affine applied later), bf16 ----
  #pragma unroll
  for (int t = 0; t < 4; ++t) {
    int co = (t << 4) + col;
    #pragma unroll
    for (int mp = 0; mp < 2; ++mp) {          // vertical pair (rows 2mp,2mp+1)
      f32x4 a0 = acc[2*mp][t], a1 = acc[2*mp+1][t];
      float mx0 = fmaxf(fmaxf(a0[0], a0[1]), fmaxf(a1[0], a1[1]));
      float mx1 = fmaxf(fmaxf(a0[2], a0[3]), fmaxf(a1[2], a1[3]));
      float mn0 = fminf(fminf(a0[0], a0[1]), fminf(a1[0], a1[1]));
      float mn1 = fminf(fminf(a0[2], a0[3]), fminf(a1[2], a1[3]));
      int pyp = (w << 1) + mp;                // pooled y
      int base = ((n*64 + co) << 6) + (pyp << 3) + (q << 1);  // feats c*64+p
      pmax2[base] = f2bf(mx0); pmax2[base+1] = f2bf(mx1);
      pmin2[base] = f2bf(mn0); pmin2[base+1] = f2bf(mn1);
    }
  }
}

// ---------------------------------------------------------------------------
// preQ partials via MFMA, fusing conv2's BN affine + ReLU into the A-frag
// load. No LDS. grid (16 mblocks x 16 ksplits), block 256.
// part layout [ks][1024][112] fp32.
// ---------------------------------------------------------------------------
__global__ __launch_bounds__(256)
void preq_mfma(const unsigned short* __restrict__ pmax2,
               const unsigned short* __restrict__ pmin2,
               const float* __restrict__ bn2,
               const unsigned short* __restrict__ qB,
               float* __restrict__ part)
{
  const int mb = blockIdx.x, ks = blockIdx.y, tid = threadIdx.x;
  const int w = tid >> 6, lane = tid & 63;
  const int q = lane >> 4, col = lane & 15;
  const int m = (mb << 6) + (w << 4) + col;    // A row this lane loads
  const int k00 = ks << 8;

  f32x4 acc[7];
  #pragma unroll
  for (int t = 0; t < 7; ++t) acc[t] = (f32x4){0.f,0.f,0.f,0.f};

  #pragma unroll 2
  for (int kk = 0; kk < 8; ++kk) {
    const int k = k00 + (kk << 5) + (q << 3);  // 8-aligned, one c per chunk
    const int c = k >> 6;
    const float sc = bn2[c], sh = bn2[64 + c];
    s8v mx = *(const s8v*)&pmax2[m*4096 + k];
    s8v mn = *(const s8v*)&pmin2[m*4096 + k];
    s8v a;
    #pragma unroll
    for (int e = 0; e < 8; ++e) {
      float vv = bf2f((unsigned short)(sc >= 0.f ? mx[e] : mn[e]));
      a[e] = (short)f2bf(fmaxf(fmaf(vv, sc, sh), 0.f));
    }
    #pragma unroll
    for (int t = 0; t < 7; ++t) {
      s8v b = *(const s8v*)&qB[(((t << 4) + col) << 12) + k];
      acc[t] = __builtin_amdgcn_mfma_f32_16x16x32_bf16(a, b, acc[t], 0, 0, 0);
    }
  }

  // C: col=lane&15 = j16, row=4q+r = m-row within the wave's 16-row tile
  float* dst = part + ks*114688 + ((mb << 6) + (w << 4) + (q << 2))*112;
  #pragma unroll
  for (int t = 0; t < 7; ++t)
    #pragma unroll
    for (int r = 0; r < 4; ++r)
      dst[r*112 + (t << 4) + col] = acc[t][r];
}

// preQ2[(t*16+b)*100+j] = sum_ks part[ks][n][j] + Qb[j], n = b*64+t.
__global__ __launch_bounds__(256)
void preq_reduce(const float* __restrict__ part, const float* __restrict__ Qb,
                 float* __restrict__ preQ2)
{
  int idx = blockIdx.x*256 + threadIdx.x;  // 102400 exact
  if (idx < 1024*100) {
    int n = idx / 100, j = idx - n*100;
    float s = Qb[j];
    #pragma unroll
    for (int ks = 0; ks < 16; ++ks) s += part[ks*114688 + n*112 + j];
    int b = n >> 6, t = n & 63;
    preQ2[((t << 4) + b)*100 + j] = s;
  }
}

// ---------------------------------------------------------------------------
// Fused RNN + head (R11 za-reformulation). One block, 512 threads (8 waves).
// Algebra: za(t) = Rwa @ Ha_a(t) obeys za = A_a*za + (1-A_a)*(Rwa@Qt), and
// Rt(t+1) = tanh(sum_a za + Rb). So the loop never touches Hf:
//   phaseQ (waves 0..6, o-tile w): Qt = ftanh(preQ + Qr@Rt); Ha update in-reg;
//     write qtB (4 ds_write_b16/wave).
//   phaseG (waves 0..5: G-tiles 4w..4w+3; wave 7: tile 24): w = G@Qt
//     (4 A-frags shared, 4-16 MFMAs, 4-way ILP); za update in-reg; sum over a
//     = 2x shfl_xor over 4 adjacent lanes; Rt = ftanh(+Rb); write rtB.
// 2 barriers/step; ~56 b128 reads + ~116 b16 writes per step (vs R9 119+140);
// max MFMA chain 4. rtB seeded with tanh(Rb) (Hf(0)=0); za(0)=0.
// ---------------------------------------------------------------------------
__global__ __launch_bounds__(512)
void rnn_fused(const float* __restrict__ preQ2,
               const unsigned short* __restrict__ gB,
               const unsigned short* __restrict__ qrB,
               const float* __restrict__ Rb,
               const float* __restrict__ Ow, const float* __restrict__ Ob,
               const float* __restrict__ f1w, const float* __restrict__ f1b,
               const float* __restrict__ f2w, const float* __restrict__ f2b,
               float* __restrict__ out)
{
  __shared__ __align__(16) unsigned short rtB[16*136];  // Rt bf16 [b][o']
  __shared__ __align__(16) unsigned short qtB[16*136];  // Qt bf16 [b][o]
  __shared__ __align__(16) float haF[6400];             // fp32 Hf for head
  __shared__ __align__(16) float olL[16*128];
  __shared__ __align__(16) float f1L[16*64];
  const int tid = threadIdx.x;
  const int w = tid >> 6, lane = tid & 63;
  const int q = lane >> 4, col = lane & 15;
  const int o = (w << 4) + col;               // phaseQ output column
  const bool qAct = (w < 7);
  const bool vO = qAct && (o < 100);

  // phaseG tile assignment: waves 0..5 -> tiles 4w..4w+3; wave 7 -> tile 24
  const int ntile = (w < 6) ? 4 : ((w == 7) ? 1 : 0);
  const int tbase = (w < 6) ? (w << 2) : 24;

  // persistent weights in VGPRs
  s8v gw[4][4], qw[4];
  #pragma unroll
  for (int tt = 0; tt < 4; ++tt)
    #pragma unroll
    for (int kk = 0; kk < 4; ++kk)
      gw[tt][kk] = (tt < ntile)
        ? *(const s8v*)&gB[((((tbase+tt)<<4)+col)<<7) + (kk<<5) + (q<<3)]
        : (s8v){0,0,0,0,0,0,0,0};
  #pragma unroll
  for (int kk = 0; kk < 4; ++kk)
    qw[kk] = qAct ? *(const s8v*)&qrB[(o<<7) + (kk<<5) + (q<<3)]
                  : (s8v){0,0,0,0,0,0,0,0};
  float rbG[4];
  #pragma unroll
  for (int tt = 0; tt < 4; ++tt) {
    int oo = ((tbase + tt) << 2) + (col >> 2);   // o' this lane-group covers
    rbG[tt] = (tt < ntile) ? Rb[oo] : 0.f;
  }

  // za decay coefficient: a = col&3 within each p-group of 4
  const int aIdx = col & 3;
  const float Aa = (aIdx==0) ? 0.f : (aIdx==1) ? 0.25f : (aIdx==2) ? 0.5f : 0.95f;
  const float Ba = 1.f - Aa;

  f32x4 za[4];
  #pragma unroll
  for (int tt = 0; tt < 4; ++tt) za[tt] = (f32x4){0.f,0.f,0.f,0.f};
  float h0[4] = {0.f,0.f,0.f,0.f}, h1[4] = {0.f,0.f,0.f,0.f};
  float h2[4] = {0.f,0.f,0.f,0.f}, h3[4] = {0.f,0.f,0.f,0.f};

  // init: rtB = bf16(tanh(Rb)) per column (Hf(0)=0); qtB = 0
  for (int i = tid; i < 2176; i += 512) {
    int b = i / 136, oo = i - b*136;
    (void)b;
    rtB[i] = (oo < 100) ? f2bf(ftanh(Rb[oo])) : (unsigned short)0;
    qtB[i] = 0;
  }
  __syncthreads();

  #pragma unroll 1
  for (int t = 0; t < 64; ++t) {
    // prefetch preQ adds (L2)
    float pq[4];
    if (qAct) {
      #pragma unroll
      for (int reg = 0; reg < 4; ++reg)
        pq[reg] = vO ? preQ2[((t << 4) + (q << 2) + reg)*100 + o] : 0.f;
    }
    // phaseQ: Qt = ftanh(preQ + Rt @ Qr^T); Ha update in-reg; write qtB
    if (qAct) {
      f32x4 a0 = (f32x4){0.f,0.f,0.f,0.f}, a1 = a0;
      #pragma unroll
      for (int kk = 0; kk < 4; ++kk) {
        s8v af = *(const s8v*)&rtB[col*136 + (kk << 5) + (q << 3)];
        if (kk & 2) a1 = __builtin_amdgcn_mfma_f32_16x16x32_bf16(af, qw[kk], a1, 0, 0, 0);
        else        a0 = __builtin_amdgcn_mfma_f32_16x16x32_bf16(af, qw[kk], a0, 0, 0, 0);
      }
      f32x4 qs = a0 + a1;
      #pragma unroll
      for (int reg = 0; reg < 4; ++reg) {
        float qt = ftanh(qs[reg] + pq[reg]);
        h0[reg] = qt;
        h1[reg] = fmaf(0.25f, h1[reg], 0.75f*qt);
        h2[reg] = fmaf(0.50f, h2[reg], 0.50f*qt);
        h3[reg] = fmaf(0.95f, h3[reg], 0.05f*qt);
        qtB[((q << 2) + reg)*136 + o] = f2bf(qt);
      }
    }
    __syncthreads();
    // phaseG: w = Qt @ G^T; za update; Rt = ftanh(sum_a za + Rb); write rtB
    if (t < 63) {
      s8v af[4];
      #pragma unroll
      for (int kk = 0; kk < 4; ++kk)
        af[kk] = *(const s8v*)&qtB[col*136 + (kk << 5) + (q << 3)];
      #pragma unroll
      for (int tt = 0; tt < 4; ++tt) {
        if (tt < ntile) {
          f32x4 acc = (f32x4){0.f,0.f,0.f,0.f};
          #pragma unroll
          for (int kk = 0; kk < 4; ++kk)
            acc = __builtin_amdgcn_mfma_f32_16x16x32_bf16(af[kk], gw[tt][kk], acc, 0, 0, 0);
          f32x4 rs;
          #pragma unroll
          for (int e = 0; e < 4; ++e) {
            za[tt][e] = fmaf(Aa, za[tt][e], Ba*acc[e]);
            float v = za[tt][e];
            v += __shfl_xor(v, 1);
            v += __shfl_xor(v, 2);
            rs[e] = v;
          }
          if ((col & 3) == 0) {
            int oo = ((tbase + tt) << 2) + (col >> 2);
            #pragma unroll
            for (int reg = 0; reg < 4; ++reg)
              rtB[((q << 2) + reg)*136 + oo] = f2bf(ftanh(rs[reg] + rbG[tt]));
          }
        }
      }
    }
    __syncthreads();
  }

  // dump fp32 Ha to LDS for the head (layout [b][a*100+o])
  if (vO) {
    #pragma unroll
    for (int reg = 0; reg < 4; ++reg) {
      int base = ((q << 2) + reg)*400 + o;
      haF[base]       = h0[reg];
      haF[base + 100] = h1[reg];
      haF[base + 200] = h2[reg];
      haF[base + 300] = h3[reg];
    }
  }
  __syncthreads();

  // head: out_last = tanh(Hf @ Ow^T + Ob)  (16x128, K=400)
  {
    const int b = tid >> 5, jb = tid & 31;
    const float* hp = &haF[b*400];
    #pragma unroll 1
    for (int jj = 0; jj < 4; ++jj) {
      int j = jb + (jj << 5);
      const float* wp = &Ow[j*400];
      float a2 = Ob[j];
      #pragma unroll 4
      for (int k = 0; k < 400; k += 4) {
        float4 h4 = *(const float4*)&hp[k];
        float4 w4 = *(const float4*)&wp[k];
        a2 = fmaf(h4.x, w4.x, fmaf(h4.y, w4.y, fmaf(h4.z, w4.z, fmaf(h4.w, w4.w, a2))));
      }
      olL[b*128 + j] = ftanh(a2);
    }
  }
  __syncthreads();
  // fc1: relu(ol @ f1w^T + f1b)  (16x64, K=128)
  {
    const int b = tid >> 5, jb = tid & 31;
    const float* op = &olL[b*128];
    #pragma unroll 1
    for (int jj = 0; jj < 2; ++jj) {
      int j = jb + (jj << 5);
      const float* wp = &f1w[j*128];
      float a2 = f1b[j];
      #pragma unroll 4
      for (int k = 0; k < 128; k += 4) {
        float4 o4 = *(const float4*)&op[k];
        float4 w4 = *(const float4*)&wp[k];
        a2 = fmaf(o4.x, w4.x, fmaf(o4.y, w4.y, fmaf(o4.z, w4.z, fmaf(o4.w, w4.w, a2))));
      }
      f1L[b*64 + j] = fmaxf(a2, 0.f);
    }
  }
  __syncthreads();
  // fc2 + sigmoid
  if (tid < 16) {
    float a2 = f2b[0];
    #pragma unroll 8
    for (int k = 0; k < 64; ++k) a2 = fmaf(f2w[k], f1L[tid*64 + k], a2);
    out[tid] = __builtin_amdgcn_rcpf(1.f + __expf(-a2));
  }
}

// ---------------------------------------------------------------------------
extern "C" void kernel_launch(void* const* d_in, const int* in_sizes, int n_in,
                              void* d_out, int out_size, void* d_ws, size_t ws_size,
                              hipStream_t stream) {
  (void)in_sizes; (void)n_in; (void)out_size; (void)ws_size;
  const float* x1   = (const float*)d_in[0];
  const float* x2   = (const float*)d_in[1];
  const float* c1w  = (const float*)d_in[2];
  // d_in[3] conv1_b: cancels in BN
  const float* bn1g = (const float*)d_in[4];
  const float* bn1b = (const float*)d_in[5];
  const float* c2w  = (const float*)d_in[6];
  // d_in[7] conv2_b: cancels in BN
  const float* bn2g = (const float*)d_in[8];
  const float* bn2b = (const float*)d_in[9];
  const float* Rw   = (const float*)d_in[10];
  const float* Rb   = (const float*)d_in[11];
  const float* Qw   = (const float*)d_in[12];
  const float* Qb   = (const float*)d_in[13];
  const float* Ow   = (const float*)d_in[14];
  const float* Ob   = (const float*)d_in[15];
  const float* f1w  = (const float*)d_in[16];
  const float* f1b  = (const float*)d_in[17];
  const float* f2w  = (const float*)d_in[18];
  const float* f2b  = (const float*)d_in[19];
  float* outp = (float*)d_out;

  // workspace layout (bytes); total ~90 MB
  char* wsb = (char*)d_ws;
  unsigned short* pmax1 = (unsigned short*)wsb;                 // 33,554,432 B
  unsigned short* pmin1 = (unsigned short*)(wsb + 33554432);    // 33,554,432 B
  unsigned short* pmax2 = (unsigned short*)(wsb + 67108864);    //  8,388,608 B
  unsigned short* pmin2 = (unsigned short*)(wsb + 75497472);    //  8,388,608 B
  float* part1  = (float*)(wsb + 83886080);                     // 524,288 B
  float* part2  = part1 + 131072;                               // 524,288 B
  float* bn1    = part2 + 131072;                               // 512 B
  float* bn2    = bn1 + 128;                                    // 512 B
  float* preQ2  = bn2 + 128;                                    // 409,600 B
  unsigned short* wB1 = (unsigned short*)(preQ2 + 102400);      // 12,288 B
  unsigned short* wB2 = wB1 + 6144;                             // 73,728 B
  unsigned short* qB  = wB2 + 36864;                            // 917,504 B
  unsigned short* gB  = qB + 458752;                            // 131,072 B (512x128)
  unsigned short* qrB = gB + 65536;                             // 32,768 B (128x128)
  float* pqpart = (float*)(qrB + 16384);                        // 7,340,032 B

  w1_pack<<<24, 256, 0, stream>>>(c1w, wB1);
  w2_pack<<<144, 256, 0, stream>>>(c2w, wB2);
  qw_pack<<<1792, 256, 0, stream>>>(Qw, qB);
  rq_pack<<<320, 256, 0, stream>>>(Rw, Qw, gB, qrB);
  conv1_mfma<<<1024, 256, 0, stream>>>(x1, x2, wB1, part1, pmax1, pmin1);
  bn_finalize<<<64, 256, 0, stream>>>(part1, bn1g, bn1b, 1.f/1048576.f, bn1);
  conv2_mfma<<<1024, 256, 0, stream>>>(pmax1, pmin1, bn1, wB2, part2, pmax2, pmin2);
  bn_finalize<<<64, 256, 0, stream>>>(part2, bn2g, bn2b, 1.f/262144.f, bn2);
  preq_mfma<<<dim3(16,16), 256, 0, stream>>>(pmax2, pmin2, bn2, qB, pqpart);
  preq_reduce<<<400, 256, 0, stream>>>(pqpart, Qb, preQ2);
  rnn_fused<<<1, 512, 0, stream>>>(preQ2, gB, qrB, Rb, Ow, Ob, f1w, f1b, f2w, f2b, outp);
}

// Round 12
// 289.799 us; speedup vs baseline: 1.0728x; 1.0728x over previous
//
#include <hip/hip_runtime.h>
#include <math.h>

// Problem constants
// x: (16,64,3,32,32) x2 concat -> (1024,6,32,32)
// conv1 6->64 k3 p1 -> BN -> ReLU -> pool2 -> (1024,64,16,16)
// conv2 64->64 k3 p1 -> BN -> ReLU -> pool2 -> (1024,64,8,8) = feats (1024,4096)
// RNN T=64 steps over feats rows n=b*64+t ; head -> sigmoid (16,1)

typedef __attribute__((ext_vector_type(8))) short s8v;   // 8 bf16 (4 VGPRs)
typedef __attribute__((ext_vector_type(4))) float f32x4;

__device__ __forceinline__ unsigned short f2bf(float f) {
  union { float f; unsigned u; } x; x.f = f;
  return (unsigned short)((x.u + 0x7FFFu + ((x.u >> 16) & 1u)) >> 16);  // RNE
}
__device__ __forceinline__ float bf2f(unsigned short u) {
  union { unsigned u; float f; } x; x.u = ((unsigned)u) << 16; return x.f;
}
// fast tanh: 1 - 2/(e^{2x}+1); inf-safe via rcp (e=inf -> 0 -> +1; e->0 -> -1)
__device__ __forceinline__ float ftanh(float x) {
  float e = __expf(2.f * x);
  return 1.f - 2.f * __builtin_amdgcn_rcpf(e + 1.f);
}

// ---------------------------------------------------------------------------
// w1 pack: fp32 [co][ci=6][kh][kw] -> bf16 [kh][64co][32k], k = kw*6+ci,
// ZEROS at k in [18,32) -- these multiply the A-side overread garbage.
// ---------------------------------------------------------------------------
__global__ __launch_bounds__(256)
void w1_pack(const float* __restrict__ w1, unsigned short* __restrict__ wB1)
{
  int i = blockIdx.x*256 + threadIdx.x;   // 3*64*32 = 6144
  if (i < 6144) {
    int kh = i >> 11, rem = i & 2047, co = rem >> 5, k2 = rem & 31;
    unsigned short v = 0;
    if (k2 < 18) {
      int kw = k2 / 6, ci = k2 - 6*kw;
      v = f2bf(w1[co*54 + ci*9 + kh*3 + kw]);
    }
    wB1[i] = v;
  }
}

// ---------------------------------------------------------------------------
// conv1 via MFMA implicit GEMM, computed ONCE. grid 1024, block 256 (4 waves).
// Epilogue: per-channel sum/sumsq + 2x2 pooled max/min bf16 channel-last.
// ---------------------------------------------------------------------------
__global__ __launch_bounds__(256, 4)
void conv1_mfma(const float* __restrict__ x1, const float* __restrict__ x2,
                const unsigned short* __restrict__ wB1,
                float* __restrict__ part,
                unsigned short* __restrict__ pmax1, unsigned short* __restrict__ pmin1)
{
  __shared__ unsigned xin[3688];          // 34 rows x 108 dwords + 16 pad
  __shared__ float wred[4][4][16][2];
  const int n = blockIdx.x, tid = threadIdx.x;
  const int w = tid >> 6, lane = tid & 63;
  const int q = lane >> 4, r = lane & 15;

  // B fragments, whole kernel in regs: bf[kh][t], co = 16t + r, k0 = 8q
  s8v bf[3][4];
  #pragma unroll
  for (int kh = 0; kh < 3; ++kh)
    #pragma unroll
    for (int t = 0; t < 4; ++t)
      bf[kh][t] = *(const s8v*)&wB1[kh*2048 + (((t<<4)+r)<<5) + (q<<3)];

  // zero ALL of xin (incl. pad tail) -- overread garbage must be finite
  #pragma unroll
  for (int k = 0; k < 15; ++k) {
    int i = tid + (k<<8);
    if (i < 3688) xin[i] = 0;
  }
  __syncthreads();
  // interior fill: dword (y+1)*108 + (x+1)*3 + cp packs bf16{ci=2cp,2cp+1}
  #pragma unroll
  for (int k = 0; k < 12; ++k) {
    int i = tid + (k<<8);     // 0..3071
    int cp = i >> 10, p = i & 1023;
    int y = p >> 5, x = p & 31;
    float lo, hi;
    if (cp == 0)      { lo = x1[n*3072 + p];        hi = x1[n*3072 + 1024 + p]; }
    else if (cp == 1) { lo = x1[n*3072 + 2048 + p]; hi = x2[n*3072 + p];        }
    else              { lo = x2[n*3072 + 1024 + p]; hi = x2[n*3072 + 2048 + p]; }
    xin[(y+1)*108 + (x+1)*3 + cp] = (unsigned)f2bf(lo) | ((unsigned)f2bf(hi) << 16);
  }
  __syncthreads();

  float st[4], sq[4];
  #pragma unroll
  for (int t = 0; t < 4; ++t) { st[t] = 0.f; sq[t] = 0.f; }
  float pmx[4][2], pmn[4][2];

  #pragma unroll 1
  for (int xb = 0; xb < 2; ++xb) {
    const int xbase = xb << 4;
    #pragma unroll 2
    for (int j = 0; j < 8; ++j) {           // y = 8w + j
      const int y = (w << 3) + j;
      f32x4 acc[4];
      #pragma unroll
      for (int t = 0; t < 4; ++t) acc[t] = (f32x4){0.f,0.f,0.f,0.f};
      #pragma unroll
      for (int kh = 0; kh < 3; ++kh) {      // k-step == kh slice
        int dw = (y + kh)*108 + 3*(xbase + r) + (q << 2);
        union { unsigned u[4]; s8v v; } af;
        af.u[0] = xin[dw];   af.u[1] = xin[dw+1];
        af.u[2] = xin[dw+2]; af.u[3] = xin[dw+3];
        #pragma unroll
        for (int t = 0; t < 4; ++t)
          acc[t] = __builtin_amdgcn_mfma_f32_16x16x32_bf16(af.v, bf[kh][t], acc[t], 0, 0, 0);
      }
      #pragma unroll
      for (int t = 0; t < 4; ++t) {
        st[t] += acc[t][0]+acc[t][1]+acc[t][2]+acc[t][3];
        sq[t] = fmaf(acc[t][0],acc[t][0], fmaf(acc[t][1],acc[t][1],
                fmaf(acc[t][2],acc[t][2], fmaf(acc[t][3],acc[t][3], sq[t]))));
      }
      if ((j & 1) == 0) {                   // even y: stash x-pair max/min
        #pragma unroll
        for (int t = 0; t < 4; ++t) {
          pmx[t][0] = fmaxf(acc[t][0], acc[t][1]); pmx[t][1] = fmaxf(acc[t][2], acc[t][3]);
          pmn[t][0] = fminf(acc[t][0], acc[t][1]); pmn[t][1] = fminf(acc[t][2], acc[t][3]);
        }
      } else {                              // odd y: combine + write pooled
        const int py = y >> 1;
        #pragma unroll
        for (int t = 0; t < 4; ++t) {
          int co = (t << 4) + r;
          #pragma unroll
          for (int pp = 0; pp < 2; ++pp) {
            float mx = fmaxf(pmx[t][pp], fmaxf(acc[t][2*pp], acc[t][2*pp+1]));
            float mn = fminf(pmn[t][pp], fminf(acc[t][2*pp], acc[t][2*pp+1]));
            int pxp = (xb << 3) + (q << 1) + pp;
            int o = (((n << 8) + (py << 4) + pxp) << 6) + co;
            pmax1[o] = f2bf(mx);
            pmin1[o] = f2bf(mn);
          }
        }
      }
    }
  }

  #pragma unroll
  for (int t = 0; t < 4; ++t) {
    float s = st[t], ss = sq[t];
    s  += __shfl_xor(s, 16);  s  += __shfl_xor(s, 32);
    ss += __shfl_xor(ss, 16); ss += __shfl_xor(ss, 32);
    if (q == 0) { wred[w][t][r][0] = s; wred[w][t][r][1] = ss; }
  }
  __syncthreads();
  if (tid < 64) {
    float s = 0.f, ss = 0.f;
    #pragma unroll
    for (int wv = 0; wv < 4; ++wv) {
      s  += wred[wv][tid >> 4][tid & 15][0];
      ss += wred[wv][tid >> 4][tid & 15][1];
    }
    part[tid*2048 + n*2]     = s;     // layout [c][n][2]
    part[tid*2048 + n*2 + 1] = ss;
  }
}

// ---------------------------------------------------------------------------
// BN finalize: per-channel mean/var -> scale/shift.  grid 64, block 256.
// ---------------------------------------------------------------------------
__global__ __launch_bounds__(256)
void bn_finalize(const float* __restrict__ part, const float* __restrict__ g,
                 const float* __restrict__ beta, float inv_cnt, float* __restrict__ bn)
{
  __shared__ float red[8];
  const int c = blockIdx.x, tid = threadIdx.x;
  float s = 0.f, ss = 0.f;
  for (int n = tid; n < 1024; n += 256) {
    s  += part[c*2048 + n*2];
    ss += part[c*2048 + n*2 + 1];
  }
  #pragma unroll
  for (int d = 32; d; d >>= 1) { s += __shfl_xor(s, d); ss += __shfl_xor(ss, d); }
  if ((tid & 63) == 0) { red[(tid>>6)*2] = s; red[(tid>>6)*2+1] = ss; }
  __syncthreads();
  if (tid == 0) {
    float S  = red[0]+red[2]+red[4]+red[6];
    float SS = red[1]+red[3]+red[5]+red[7];
    float m  = S * inv_cnt;
    float var = SS * inv_cnt - m*m;
    float sc = g[c] * rsqrtf(var + 1e-5f);
    bn[c]    = sc;
    bn[64+c] = beta[c] - m*sc;
  }
}

// ---------------------------------------------------------------------------
// w2 pack: fp32 [co][ci][kh][kw] -> bf16 [khw][co][ci] with the ci-chunk
// XOR-swizzle ((ci>>3)^(co&7)) pre-applied so conv2's LDS copy is linear.
// ---------------------------------------------------------------------------
__global__ __launch_bounds__(256)
void w2_pack(const float* __restrict__ w2, unsigned short* __restrict__ wB)
{
  int i = blockIdx.x*256 + threadIdx.x;   // 9*64*64 = 36864
  if (i < 36864) {
    int khw = i >> 12, rem = i & 4095, co = rem >> 6, ci = rem & 63;
    int chunk = (ci >> 3) ^ (co & 7);
    wB[khw*4096 + co*64 + chunk*8 + (ci & 7)] = f2bf(w2[co*576 + ci*9 + khw]);
  }
}

// ---------------------------------------------------------------------------
// Qw pack: fp32 [100][4196] (first 4096 cols) -> bf16 [112][4096],
// rows 100..111 zeroed (N padded to 7x16 MFMA tiles).
// ---------------------------------------------------------------------------
__global__ __launch_bounds__(256)
void qw_pack(const float* __restrict__ Qw, unsigned short* __restrict__ qB)
{
  int i = blockIdx.x*256 + threadIdx.x;   // 112*4096 = 458752
  if (i < 458752) {
    int j = i >> 12, k = i & 4095;
    qB[i] = (j < 100) ? f2bf(Qw[j*4196 + k]) : (unsigned short)0;
  }
}

// ---------------------------------------------------------------------------
// RNN weight pack (za-reformulation):
//  gB bf16 [512 p][128 k]: G[p=4*o'+a][k=o] = Rw[o'][a*100+o]; zero padded.
//  qrB bf16 [128 o][128 kr]: Qw recurrent cols, zero padded.
// ---------------------------------------------------------------------------
__global__ __launch_bounds__(256)
void rq_pack(const float* __restrict__ Rw, const float* __restrict__ Qw,
             unsigned short* __restrict__ gB, unsigned short* __restrict__ qrB)
{
  int i = blockIdx.x*256 + threadIdx.x;   // 65536 + 16384 = 81920
  if (i < 65536) {
    int p = i >> 7, k = i & 127;
    unsigned short v = 0;
    if (p < 400 && k < 100) v = f2bf(Rw[(p >> 2)*400 + (p & 3)*100 + k]);
    gB[i] = v;
  } else if (i < 81920) {
    int j = i - 65536;
    int o = j >> 7, kr = j & 127;
    qrB[j] = (o < 100 && kr < 100) ? f2bf(Qw[o*4196 + 4096 + kr]) : (unsigned short)0;
  }
}

// ---------------------------------------------------------------------------
// conv2 via MFMA implicit GEMM. grid 1024 (one image), block 256 (4 waves).
// Staging FUSES conv1's BN affine + ReLU. Pooled raw outputs stored bf16.
// ---------------------------------------------------------------------------
__global__ __launch_bounds__(256)
void conv2_mfma(const unsigned short* __restrict__ pmax1,
                const unsigned short* __restrict__ pmin1,
                const float* __restrict__ bn1,
                const unsigned short* __restrict__ wB,
                float* __restrict__ part,
                unsigned short* __restrict__ pmax2, unsigned short* __restrict__ pmin2)
{
  __shared__ unsigned short xin[324*64];   // 41472 B
  __shared__ unsigned short wL[9*64*64];   // 73728 B
  __shared__ float wred[4][4][16][2];      // 2 KB
  __shared__ float bnL[128];
  const int n = blockIdx.x, tid = threadIdx.x;
  const int w = tid >> 6, lane = tid & 63;
  const int q = lane >> 4, col = lane & 15;

  if (tid < 128) bnL[tid] = bn1[tid];
  // ---- stage weights (linear copy; swizzle pre-applied by w2_pack) ----
  {
    const s8v* src = (const s8v*)wB;
    s8v* dst = (s8v*)wL;
    #pragma unroll
    for (int i = 0; i < 18; ++i) dst[tid + (i<<8)] = src[tid + (i<<8)];
  }
  __syncthreads();   // bnL ready
  // ---- stage input 18x18x64 bf16 = relu(affine(pooled conv1)), halo zeros,
  //      swizzled 16B chunks ----
  {
    #pragma unroll
    for (int k = 0; k < 11; ++k) {
      int i = tid + (k<<8);
      if (i < 324*8) {
        int L = i >> 3, s = i & 7;
        int y = L / 18, x = L - y*18;
        s8v v = (s8v){0,0,0,0,0,0,0,0};
        if (y >= 1 && y <= 16 && x >= 1 && x <= 16) {
          int idx = (((n<<8) + ((y-1)<<4) + (x-1))<<6) + (s<<3);
          s8v mx = *(const s8v*)&pmax1[idx];
          s8v mn = *(const s8v*)&pmin1[idx];
          #pragma unroll
          for (int e = 0; e < 8; ++e) {
            int ci = (s<<3) + e;
            float sc = bnL[ci], sh = bnL[64+ci];
            float vv = bf2f((unsigned short)(sc >= 0.f ? mx[e] : mn[e]));
            v[e] = (short)f2bf(fmaxf(fmaf(vv, sc, sh), 0.f));
          }
        }
        *(s8v*)((char*)xin + L*128 + (((s ^ (L & 7)) << 4))) = v;
      }
    }
  }
  __syncthreads();

  f32x4 acc[4][4];   // [mtile][ntile]
  #pragma unroll
  for (int mt = 0; mt < 4; ++mt)
    #pragma unroll
    for (int t = 0; t < 4; ++t)
      acc[mt][t] = (f32x4){0.f,0.f,0.f,0.f};

  const int py0 = w << 2;   // wave's 4 image rows
  #pragma unroll 1
  for (int khw = 0; khw < 9; ++khw) {
    const int kh = khw / 3, kw = khw - 3*kh;
    const char* wslice = (const char*)wL + khw*8192;
    #pragma unroll
    for (int ks = 0; ks < 2; ++ks) {       // ci0 = 32*ks
      const int chunk = (ks << 2) + q;     // 16B-chunk of k within line
      s8v bfrag[4];
      #pragma unroll
      for (int t = 0; t < 4; ++t) {
        int co = (t << 4) + col;
        bfrag[t] = *(const s8v*)(wslice + co*128 + (((chunk ^ (co & 7)) << 4)));
      }
      #pragma unroll
      for (int mt = 0; mt < 4; ++mt) {
        int L = (py0 + mt + kh)*18 + (col + kw);
        s8v afrag = *(const s8v*)((const char*)xin + L*128 + (((chunk ^ (L & 7)) << 4)));
        #pragma unroll
        for (int t = 0; t < 4; ++t)
          acc[mt][t] = __builtin_amdgcn_mfma_f32_16x16x32_bf16(afrag, bfrag[t], acc[mt][t], 0, 0, 0);
      }
    }
  }

  // ---- stats: per-channel sum / sumsq over this block's 256 pixels ----
  #pragma unroll
  for (int t = 0; t < 4; ++t) {
    float s = 0.f, ss = 0.f;
    #pragma unroll
    for (int mt = 0; mt < 4; ++mt)
      #pragma unroll
      for (int r = 0; r < 4; ++r) {
        float v = acc[mt][t][r];
        s += v; ss = fmaf(v, v, ss);
      }
    s  += __shfl_xor(s, 16);  s  += __shfl_xor(s, 32);
    ss += __shfl_xor(ss, 16); ss += __shfl_xor(ss, 32);
    if (q == 0) { wred[w][t][col][0] = s; wred[w][t][col][1] = ss; }
  }
  __syncthreads();
  if (tid < 64) {
    float s = 0.f, ss = 0.f;
    #pragma unroll
    for (int wv = 0; wv < 4; ++wv) {
      s  += wred[wv][tid >> 4][tid & 15][0];
      ss += wred[wv][tid >> 4][tid & 15][1];
    }
    part[tid*2048 + n*2]     = s;
    part[tid*2048 + n*2 + 1] = ss;
  }

  // ---- 2x2 pooled max AND min of raw conv (affine applied later), bf16 ----
  #pragma unroll
  for (int t = 0; t < 4; ++t) {
    int co = (t << 4) + col;
    #pragma unroll
    for (int mp = 0; mp < 2; ++mp) {          // vertical pair (rows 2mp,2mp+1)
      f32x4 a0 = acc[2*mp][t], a1 = acc[2*mp+1][t];
      float mx0 = fmaxf(fmaxf(a0[0], a0[1]), fmaxf(a1[0], a1[1]));
      float mx1 = fmaxf(fmaxf(a0[2], a0[3]), fmaxf(a1[2], a1[3]));
      float mn0 = fminf(fminf(a0[0], a0[1]), fminf(a1[0], a1[1]));
      float mn1 = fminf(fminf(a0[2], a0[3]), fminf(a1[2], a1[3]));
      int pyp = (w << 1) + mp;                // pooled y
      int base = ((n*64 + co) << 6) + (pyp << 3) + (q << 1);  // feats c*64+p
      pmax2[base] = f2bf(mx0); pmax2[base+1] = f2bf(mx1);
      pmin2[base] = f2bf(mn0); pmin2[base+1] = f2bf(mn1);
    }
  }
}

// ---------------------------------------------------------------------------
// preQ partials via MFMA, fusing conv2's BN affine + ReLU into the A-frag
// load. No LDS. grid (16 mblocks x 16 ksplits), block 256.
// part layout [ks][1024][112] fp32.
// ---------------------------------------------------------------------------
__global__ __launch_bounds__(256)
void preq_mfma(const unsigned short* __restrict__ pmax2,
               const unsigned short* __restrict__ pmin2,
               const float* __restrict__ bn2,
               const unsigned short* __restrict__ qB,
               float* __restrict__ part)
{
  const int mb = blockIdx.x, ks = blockIdx.y, tid = threadIdx.x;
  const int w = tid >> 6, lane = tid & 63;
  const int q = lane >> 4, col = lane & 15;
  const int m = (mb << 6) + (w << 4) + col;    // A row this lane loads
  const int k00 = ks << 8;

  f32x4 acc[7];
  #pragma unroll
  for (int t = 0; t < 7; ++t) acc[t] = (f32x4){0.f,0.f,0.f,0.f};

  #pragma unroll 2
  for (int kk = 0; kk < 8; ++kk) {
    const int k = k00 + (kk << 5) + (q << 3);  // 8-aligned, one c per chunk
    const int c = k >> 6;
    const float sc = bn2[c], sh = bn2[64 + c];
    s8v mx = *(const s8v*)&pmax2[m*4096 + k];
    s8v mn = *(const s8v*)&pmin2[m*4096 + k];
    s8v a;
    #pragma unroll
    for (int e = 0; e < 8; ++e) {
      float vv = bf2f((unsigned short)(sc >= 0.f ? mx[e] : mn[e]));
      a[e] = (short)f2bf(fmaxf(fmaf(vv, sc, sh), 0.f));
    }
    #pragma unroll
    for (int t = 0; t < 7; ++t) {
      s8v b = *(const s8v*)&qB[(((t << 4) + col) << 12) + k];
      acc[t] = __builtin_amdgcn_mfma_f32_16x16x32_bf16(a, b, acc[t], 0, 0, 0);
    }
  }

  // C: col=lane&15 = j16, row=4q+r = m-row within the wave's 16-row tile
  float* dst = part + ks*114688 + ((mb << 6) + (w << 4) + (q << 2))*112;
  #pragma unroll
  for (int t = 0; t < 7; ++t)
    #pragma unroll
    for (int r = 0; r < 4; ++r)
      dst[r*112 + (t << 4) + col] = acc[t][r];
}

// preQ3[b4][t][o][b&3] = sum_ks part[ks][n][j] + Qb[j], n = b*64+t.
// Layout is block-linear for rnn_fused's LDS staging (b4 = b>>2).
__global__ __launch_bounds__(256)
void preq_reduce(const float* __restrict__ part, const float* __restrict__ Qb,
                 float* __restrict__ preQ3)
{
  int idx = blockIdx.x*256 + threadIdx.x;  // 102400 exact
  if (idx < 1024*100) {
    int n = idx / 100, j = idx - n*100;
    float s = Qb[j];
    #pragma unroll
    for (int ks = 0; ks < 16; ++ks) s += part[ks*114688 + n*112 + j];
    int b = n >> 6, t = n & 63;
    preQ3[(b >> 2)*25600 + t*400 + j*4 + (b & 3)] = s;
  }
}

// ---------------------------------------------------------------------------
// Fused RNN + head (R12). grid 4 blocks x 4 batches, 512 threads (8 waves).
// R11 post-mortem: ~70% of each step was stall -- per-step preQ global load
// (HBM ~900cyc + vmcnt drain at barrier) and long serial chains. Fixes:
//  - preQ staged ONCE into LDS (102 KB fp32, layout [t][o][b] -> one b128
//    read per lane per step). ZERO global traffic in the loop.
//  - M=4 (4 batches): G-phase = 25 exact tiles spread 3-4/wave (ILP),
//    Q-phase 7 tiles; za/Ha in registers; shfl_xor(1/2) = quad DPP.
//  - 2 barriers/step.
// ---------------------------------------------------------------------------
__global__ __launch_bounds__(512, 2)
void rnn_fused(const float* __restrict__ preQ3,
               const unsigned short* __restrict__ gB,
               const unsigned short* __restrict__ qrB,
               const float* __restrict__ Rb,
               const float* __restrict__ Ow, const float* __restrict__ Ob,
               const float* __restrict__ f1w, const float* __restrict__ f1b,
               const float* __restrict__ f2w, const float* __restrict__ f2b,
               float* __restrict__ out)
{
  __shared__ __align__(16) float pqL[25600];            // [t][o][b] fp32, 100 KB
  __shared__ __align__(16) unsigned short rtB[16*136];  // Rt bf16 [b][o'], rows 4-15 zero
  __shared__ __align__(16) unsigned short qtB[16*136];  // Qt bf16 [b][o], rows 4-15 zero
  __shared__ __align__(16) float haF[4*400];
  __shared__ __align__(16) float olL[4*128];
  __shared__ __align__(16) float f1L[4*64];
  const int tid = threadIdx.x;
  const int w = tid >> 6, lane = tid & 63;
  const int q = lane >> 4, col = lane & 15;
  const int b4 = blockIdx.x;

  // ---- stage this block's preQ slice into LDS (one-time) ----
  {
    const float4* src = (const float4*)(preQ3 + b4*25600);
    float4* dst = (float4*)pqL;
    #pragma unroll 1
    for (int i = tid; i < 6400; i += 512) dst[i] = src[i];
  }

  // ---- persistent weights in VGPRs ----
  const int oQ = (w << 4) + col;          // phaseQ column (valid < 100)
  const bool vQ = (w < 7);
  const bool vO = vQ && (oQ < 100);
  s8v qw[4];
  #pragma unroll
  for (int kk = 0; kk < 4; ++kk)
    qw[kk] = vQ ? *(const s8v*)&qrB[(oQ << 7) + (kk << 5) + (q << 3)]
                : (s8v){0,0,0,0,0,0,0,0};

  const int NT = (w == 7) ? 4 : 3;        // phaseG tiles per wave (25 total)
  int tIdx[4];
  tIdx[0] = w; tIdx[1] = w + 8; tIdx[2] = w + 16; tIdx[3] = 24;
  s8v gw[4][4];
  float rbG[4];
  #pragma unroll
  for (int j = 0; j < 4; ++j) {
    int p = (tIdx[j] << 4) + col;         // G row, p < 400 for active tiles
    #pragma unroll
    for (int kk = 0; kk < 4; ++kk)
      gw[j][kk] = (j < NT) ? *(const s8v*)&gB[(p << 7) + (kk << 5) + (q << 3)]
                           : (s8v){0,0,0,0,0,0,0,0};
    rbG[j] = (j < NT) ? Rb[p >> 2] : 0.f;
  }

  const int aIdx = col & 3;
  const float Aa = (aIdx==0) ? 0.f : (aIdx==1) ? 0.25f : (aIdx==2) ? 0.5f : 0.95f;
  const float Ba = 1.f - Aa;

  f32x4 za0 = (f32x4){0.f,0.f,0.f,0.f}, za1 = za0, za2 = za0, za3 = za0;
  float h0[4] = {0.f,0.f,0.f,0.f}, h1[4] = {0.f,0.f,0.f,0.f};
  float h2[4] = {0.f,0.f,0.f,0.f}, h3[4] = {0.f,0.f,0.f,0.f};

  // init rtB = tanh(Rb) on rows 0-3 (Hf(0)=0); everything else zero
  #pragma unroll 1
  for (int i = tid; i < 2176; i += 512) {
    int r = i / 136, oo = i - r*136;
    rtB[i] = (r < 4 && oo < 100) ? f2bf(ftanh(Rb[oo])) : (unsigned short)0;
    qtB[i] = 0;
  }
  __syncthreads();

  #pragma unroll 1
  for (int t = 0; t < 64; ++t) {
    // ---- phaseQ: Qt = ftanh(pq + Rt @ Qr^T); Ha update in-reg ----
    if (vQ) {
      f32x4 a0 = (f32x4){0.f,0.f,0.f,0.f}, a1 = a0;
      #pragma unroll
      for (int kk = 0; kk < 4; ++kk) {
        s8v af = *(const s8v*)&rtB[col*136 + (kk << 5) + (q << 3)];
        if (kk & 1) a1 = __builtin_amdgcn_mfma_f32_16x16x32_bf16(af, qw[kk], a1, 0, 0, 0);
        else        a0 = __builtin_amdgcn_mfma_f32_16x16x32_bf16(af, qw[kk], a0, 0, 0, 0);
      }
      f32x4 qs = a0 + a1;
      if (q == 0 && oQ < 100) {
        f32x4 pq4 = *(const f32x4*)&pqL[t*400 + (oQ << 2)];  // 4 batches of this o
        #pragma unroll
        for (int reg = 0; reg < 4; ++reg) {
          float qt = ftanh(qs[reg] + pq4[reg]);
          h0[reg] = qt;
          h1[reg] = fmaf(0.25f, h1[reg], 0.75f*qt);
          h2[reg] = fmaf(0.50f, h2[reg], 0.50f*qt);
          h3[reg] = fmaf(0.95f, h3[reg], 0.05f*qt);
          qtB[reg*136 + oQ] = f2bf(qt);
        }
      }
    }
    __syncthreads();
    // ---- phaseG: w = Qt @ G^T; za update; Rt = ftanh(sum_a za + Rb) ----
    if (t < 63) {
      s8v af[4];
      #pragma unroll
      for (int kk = 0; kk < 4; ++kk)
        af[kk] = *(const s8v*)&qtB[col*136 + (kk << 5) + (q << 3)];
      #pragma unroll
      for (int j = 0; j < 4; ++j) {
        if (j < NT) {
          f32x4 acc = (f32x4){0.f,0.f,0.f,0.f};
          #pragma unroll
          for (int kk = 0; kk < 4; ++kk)
            acc = __builtin_amdgcn_mfma_f32_16x16x32_bf16(af[kk], gw[j][kk], acc, 0, 0, 0);
          f32x4* zp = (j == 0) ? &za0 : (j == 1) ? &za1 : (j == 2) ? &za2 : &za3;
          #pragma unroll
          for (int e = 0; e < 4; ++e) {
            float z = fmaf(Aa, (*zp)[e], Ba*acc[e]);
            (*zp)[e] = z;
            z += __shfl_xor(z, 1);
            z += __shfl_xor(z, 2);
            if (q == 0 && aIdx == 0)
              rtB[e*136 + (((tIdx[j] << 4) + col) >> 2)] = f2bf(ftanh(z + rbG[j]));
          }
        }
      }
    }
    __syncthreads();
  }

  // ---- dump Ha to LDS for the head: haF[b][a*100+o] ----
  if (vO && q == 0) {
    #pragma unroll
    for (int reg = 0; reg < 4; ++reg) {
      int base = reg*400 + oQ;
      haF[base]       = h0[reg];
      haF[base + 100] = h1[reg];
      haF[base + 200] = h2[reg];
      haF[base + 300] = h3[reg];
    }
  }
  __syncthreads();

  // head: ol = tanh(Hf @ Ow^T + Ob): tid -> (b = tid>>7, j = tid&127)
  {
    const int b = tid >> 7, j = tid & 127;
    const float* hp = &haF[b*400];
    const float* wp = &Ow[j*400];
    float a2 = Ob[j];
    #pragma unroll 4
    for (int k = 0; k < 400; k += 4) {
      float4 h4 = *(const float4*)&hp[k];
      float4 w4 = *(const float4*)&wp[k];
      a2 = fmaf(h4.x, w4.x, fmaf(h4.y, w4.y, fmaf(h4.z, w4.z, fmaf(h4.w, w4.w, a2))));
    }
    olL[b*128 + j] = ftanh(a2);
  }
  __syncthreads();
  // fc1: relu(ol @ f1w^T + f1b): tid<256 -> (b = tid>>6, j = tid&63)
  if (tid < 256) {
    const int b = tid >> 6, j = tid & 63;
    const float* op = &olL[b*128];
    const float* wp = &f1w[j*128];
    float a2 = f1b[j];
    #pragma unroll 4
    for (int k = 0; k < 128; k += 4) {
      float4 o4 = *(const float4*)&op[k];
      float4 w4 = *(const float4*)&wp[k];
      a2 = fmaf(o4.x, w4.x, fmaf(o4.y, w4.y, fmaf(o4.z, w4.z, fmaf(o4.w, w4.w, a2))));
    }
    f1L[b*64 + j] = fmaxf(a2, 0.f);
  }
  __syncthreads();
  // fc2 + sigmoid
  if (tid < 4) {
    float a2 = f2b[0];
    #pragma unroll 8
    for (int k = 0; k < 64; ++k) a2 = fmaf(f2w[k], f1L[tid*64 + k], a2);
    out[(b4 << 2) + tid] = __builtin_amdgcn_rcpf(1.f + __expf(-a2));
  }
}

// ---------------------------------------------------------------------------
extern "C" void kernel_launch(void* const* d_in, const int* in_sizes, int n_in,
                              void* d_out, int out_size, void* d_ws, size_t ws_size,
                              hipStream_t stream) {
  (void)in_sizes; (void)n_in; (void)out_size; (void)ws_size;
  const float* x1   = (const float*)d_in[0];
  const float* x2   = (const float*)d_in[1];
  const float* c1w  = (const float*)d_in[2];
  // d_in[3] conv1_b: cancels in BN
  const float* bn1g = (const float*)d_in[4];
  const float* bn1b = (const float*)d_in[5];
  const float* c2w  = (const float*)d_in[6];
  // d_in[7] conv2_b: cancels in BN
  const float* bn2g = (const float*)d_in[8];
  const float* bn2b = (const float*)d_in[9];
  const float* Rw   = (const float*)d_in[10];
  const float* Rb   = (const float*)d_in[11];
  const float* Qw   = (const float*)d_in[12];
  const float* Qb   = (const float*)d_in[13];
  const float* Ow   = (const float*)d_in[14];
  const float* Ob   = (const float*)d_in[15];
  const float* f1w  = (const float*)d_in[16];
  const float* f1b  = (const float*)d_in[17];
  const float* f2w  = (const float*)d_in[18];
  const float* f2b  = (const float*)d_in[19];
  float* outp = (float*)d_out;

  // workspace layout (bytes); total ~90 MB
  char* wsb = (char*)d_ws;
  unsigned short* pmax1 = (unsigned short*)wsb;                 // 33,554,432 B
  unsigned short* pmin1 = (unsigned short*)(wsb + 33554432);    // 33,554,432 B
  unsigned short* pmax2 = (unsigned short*)(wsb + 67108864);    //  8,388,608 B
  unsigned short* pmin2 = (unsigned short*)(wsb + 75497472);    //  8,388,608 B
  float* part1  = (float*)(wsb + 83886080);                     // 524,288 B
  float* part2  = part1 + 131072;                               // 524,288 B
  float* bn1    = part2 + 131072;                               // 512 B
  float* bn2    = bn1 + 128;                                    // 512 B
  float* preQ3  = bn2 + 128;                                    // 409,600 B
  unsigned short* wB1 = (unsigned short*)(preQ3 + 102400);      // 12,288 B
  unsigned short* wB2 = wB1 + 6144;                             // 73,728 B
  unsigned short* qB  = wB2 + 36864;                            // 917,504 B
  unsigned short* gB  = qB + 458752;                            // 131,072 B (512x128)
  unsigned short* qrB = gB + 65536;                             // 32,768 B (128x128)
  float* pqpart = (float*)(qrB + 16384);                        // 7,340,032 B

  w1_pack<<<24, 256, 0, stream>>>(c1w, wB1);
  w2_pack<<<144, 256, 0, stream>>>(c2w, wB2);
  qw_pack<<<1792, 256, 0, stream>>>(Qw, qB);
  rq_pack<<<320, 256, 0, stream>>>(Rw, Qw, gB, qrB);
  conv1_mfma<<<1024, 256, 0, stream>>>(x1, x2, wB1, part1, pmax1, pmin1);
  bn_finalize<<<64, 256, 0, stream>>>(part1, bn1g, bn1b, 1.f/1048576.f, bn1);
  conv2_mfma<<<1024, 256, 0, stream>>>(pmax1, pmin1, bn1, wB2, part2, pmax2, pmin2);
  bn_finalize<<<64, 256, 0, stream>>>(part2, bn2g, bn2b, 1.f/262144.f, bn2);
  preq_mfma<<<dim3(16,16), 256, 0, stream>>>(pmax2, pmin2, bn2, qB, pqpart);
  preq_reduce<<<400, 256, 0, stream>>>(pqpart, Qb, preQ3);
  rnn_fused<<<4, 512, 0, stream>>>(preQ3, gB, qrB, Rb, Ow, Ob, f1w, f1b, f2w, f2b, outp);
}

// Round 13
// 193.786 us; speedup vs baseline: 1.6043x; 1.4955x over previous
//
#include <hip/hip_runtime.h>
#include <math.h>

// Problem constants
// x: (16,64,3,32,32) x2 concat -> (1024,6,32,32)
// conv1 6->64 k3 p1 -> BN -> ReLU -> pool2 -> (1024,64,16,16)
// conv2 64->64 k3 p1 -> BN -> ReLU -> pool2 -> (1024,64,8,8) = feats (1024,4096)
// RNN T=64 steps over feats rows n=b*64+t ; head -> sigmoid (16,1)
//
// R13 NOTE: R8-R12 RNN redesigns (MFMA batched, za-reform, LDS-preQ) ALL lost
// to R7's simple per-batch VALU version (94us) -- compiler demoted "persistent
// weight registers" to scratch (VGPR_Count 64-112 << required), adding in-loop
// reload latency. Reverted to R7 structure; ONLY change: libm tanhf -> ftanh
// (exp+rcp), sigmoid via __expf. One controlled variable.

typedef __attribute__((ext_vector_type(8))) short s8v;   // 8 bf16 (4 VGPRs)
typedef __attribute__((ext_vector_type(4))) float f32x4;

__device__ __forceinline__ unsigned short f2bf(float f) {
  union { float f; unsigned u; } x; x.f = f;
  return (unsigned short)((x.u + 0x7FFFu + ((x.u >> 16) & 1u)) >> 16);  // RNE
}
__device__ __forceinline__ float bf2f(unsigned short u) {
  union { unsigned u; float f; } x; x.u = ((unsigned)u) << 16; return x.f;
}
// fast tanh: 1 - 2/(e^{2x}+1); inf-safe via rcp (e=inf -> 0 -> +1; e->0 -> -1)
__device__ __forceinline__ float ftanh(float x) {
  float e = __expf(2.f * x);
  return 1.f - 2.f * __builtin_amdgcn_rcpf(e + 1.f);
}

// ---------------------------------------------------------------------------
// w1 pack: fp32 [co][ci=6][kh][kw] -> bf16 [kh][64co][32k], k = kw*6+ci,
// ZEROS at k in [18,32) -- these multiply the A-side overread garbage.
// ---------------------------------------------------------------------------
__global__ __launch_bounds__(256)
void w1_pack(const float* __restrict__ w1, unsigned short* __restrict__ wB1)
{
  int i = blockIdx.x*256 + threadIdx.x;   // 3*64*32 = 6144
  if (i < 6144) {
    int kh = i >> 11, rem = i & 2047, co = rem >> 5, k2 = rem & 31;
    unsigned short v = 0;
    if (k2 < 18) {
      int kw = k2 / 6, ci = k2 - 6*kw;
      v = f2bf(w1[co*54 + ci*9 + kh*3 + kw]);
    }
    wB1[i] = v;
  }
}

// ---------------------------------------------------------------------------
// conv1 via MFMA implicit GEMM, computed ONCE. grid 1024, block 256 (4 waves).
// Epilogue: per-channel sum/sumsq + 2x2 pooled max/min bf16 channel-last.
// ---------------------------------------------------------------------------
__global__ __launch_bounds__(256, 4)
void conv1_mfma(const float* __restrict__ x1, const float* __restrict__ x2,
                const unsigned short* __restrict__ wB1,
                float* __restrict__ part,
                unsigned short* __restrict__ pmax1, unsigned short* __restrict__ pmin1)
{
  __shared__ unsigned xin[3688];          // 34 rows x 108 dwords + 16 pad
  __shared__ float wred[4][4][16][2];
  const int n = blockIdx.x, tid = threadIdx.x;
  const int w = tid >> 6, lane = tid & 63;
  const int q = lane >> 4, r = lane & 15;

  // B fragments, whole kernel in regs: bf[kh][t], co = 16t + r, k0 = 8q
  s8v bf[3][4];
  #pragma unroll
  for (int kh = 0; kh < 3; ++kh)
    #pragma unroll
    for (int t = 0; t < 4; ++t)
      bf[kh][t] = *(const s8v*)&wB1[kh*2048 + (((t<<4)+r)<<5) + (q<<3)];

  // zero ALL of xin (incl. pad tail) -- overread garbage must be finite
  #pragma unroll
  for (int k = 0; k < 15; ++k) {
    int i = tid + (k<<8);
    if (i < 3688) xin[i] = 0;
  }
  __syncthreads();
  // interior fill: dword (y+1)*108 + (x+1)*3 + cp packs bf16{ci=2cp,2cp+1}
  #pragma unroll
  for (int k = 0; k < 12; ++k) {
    int i = tid + (k<<8);     // 0..3071
    int cp = i >> 10, p = i & 1023;
    int y = p >> 5, x = p & 31;
    float lo, hi;
    if (cp == 0)      { lo = x1[n*3072 + p];        hi = x1[n*3072 + 1024 + p]; }
    else if (cp == 1) { lo = x1[n*3072 + 2048 + p]; hi = x2[n*3072 + p];        }
    else              { lo = x2[n*3072 + 1024 + p]; hi = x2[n*3072 + 2048 + p]; }
    xin[(y+1)*108 + (x+1)*3 + cp] = (unsigned)f2bf(lo) | ((unsigned)f2bf(hi) << 16);
  }
  __syncthreads();

  float st[4], sq[4];
  #pragma unroll
  for (int t = 0; t < 4; ++t) { st[t] = 0.f; sq[t] = 0.f; }
  float pmx[4][2], pmn[4][2];

  #pragma unroll 1
  for (int xb = 0; xb < 2; ++xb) {
    const int xbase = xb << 4;
    #pragma unroll 2
    for (int j = 0; j < 8; ++j) {           // y = 8w + j
      const int y = (w << 3) + j;
      f32x4 acc[4];
      #pragma unroll
      for (int t = 0; t < 4; ++t) acc[t] = (f32x4){0.f,0.f,0.f,0.f};
      #pragma unroll
      for (int kh = 0; kh < 3; ++kh) {      // k-step == kh slice
        int dw = (y + kh)*108 + 3*(xbase + r) + (q << 2);
        union { unsigned u[4]; s8v v; } af;
        af.u[0] = xin[dw];   af.u[1] = xin[dw+1];
        af.u[2] = xin[dw+2]; af.u[3] = xin[dw+3];
        #pragma unroll
        for (int t = 0; t < 4; ++t)
          acc[t] = __builtin_amdgcn_mfma_f32_16x16x32_bf16(af.v, bf[kh][t], acc[t], 0, 0, 0);
      }
      #pragma unroll
      for (int t = 0; t < 4; ++t) {
        st[t] += acc[t][0]+acc[t][1]+acc[t][2]+acc[t][3];
        sq[t] = fmaf(acc[t][0],acc[t][0], fmaf(acc[t][1],acc[t][1],
                fmaf(acc[t][2],acc[t][2], fmaf(acc[t][3],acc[t][3], sq[t]))));
      }
      if ((j & 1) == 0) {                   // even y: stash x-pair max/min
        #pragma unroll
        for (int t = 0; t < 4; ++t) {
          pmx[t][0] = fmaxf(acc[t][0], acc[t][1]); pmx[t][1] = fmaxf(acc[t][2], acc[t][3]);
          pmn[t][0] = fminf(acc[t][0], acc[t][1]); pmn[t][1] = fminf(acc[t][2], acc[t][3]);
        }
      } else {                              // odd y: combine + write pooled
        const int py = y >> 1;
        #pragma unroll
        for (int t = 0; t < 4; ++t) {
          int co = (t << 4) + r;
          #pragma unroll
          for (int pp = 0; pp < 2; ++pp) {
            float mx = fmaxf(pmx[t][pp], fmaxf(acc[t][2*pp], acc[t][2*pp+1]));
            float mn = fminf(pmn[t][pp], fminf(acc[t][2*pp], acc[t][2*pp+1]));
            int pxp = (xb << 3) + (q << 1) + pp;
            int o = (((n << 8) + (py << 4) + pxp) << 6) + co;
            pmax1[o] = f2bf(mx);
            pmin1[o] = f2bf(mn);
          }
        }
      }
    }
  }

  #pragma unroll
  for (int t = 0; t < 4; ++t) {
    float s = st[t], ss = sq[t];
    s  += __shfl_xor(s, 16);  s  += __shfl_xor(s, 32);
    ss += __shfl_xor(ss, 16); ss += __shfl_xor(ss, 32);
    if (q == 0) { wred[w][t][r][0] = s; wred[w][t][r][1] = ss; }
  }
  __syncthreads();
  if (tid < 64) {
    float s = 0.f, ss = 0.f;
    #pragma unroll
    for (int wv = 0; wv < 4; ++wv) {
      s  += wred[wv][tid >> 4][tid & 15][0];
      ss += wred[wv][tid >> 4][tid & 15][1];
    }
    part[tid*2048 + n*2]     = s;     // layout [c][n][2]
    part[tid*2048 + n*2 + 1] = ss;
  }
}

// ---------------------------------------------------------------------------
// BN finalize: per-channel mean/var -> scale/shift.  grid 64, block 256.
// ---------------------------------------------------------------------------
__global__ __launch_bounds__(256)
void bn_finalize(const float* __restrict__ part, const float* __restrict__ g,
                 const float* __restrict__ beta, float inv_cnt, float* __restrict__ bn)
{
  __shared__ float red[8];
  const int c = blockIdx.x, tid = threadIdx.x;
  float s = 0.f, ss = 0.f;
  for (int n = tid; n < 1024; n += 256) {
    s  += part[c*2048 + n*2];
    ss += part[c*2048 + n*2 + 1];
  }
  #pragma unroll
  for (int d = 32; d; d >>= 1) { s += __shfl_xor(s, d); ss += __shfl_xor(ss, d); }
  if ((tid & 63) == 0) { red[(tid>>6)*2] = s; red[(tid>>6)*2+1] = ss; }
  __syncthreads();
  if (tid == 0) {
    float S  = red[0]+red[2]+red[4]+red[6];
    float SS = red[1]+red[3]+red[5]+red[7];
    float m  = S * inv_cnt;
    float var = SS * inv_cnt - m*m;
    float sc = g[c] * rsqrtf(var + 1e-5f);
    bn[c]    = sc;
    bn[64+c] = beta[c] - m*sc;
  }
}

// ---------------------------------------------------------------------------
// w2 pack: fp32 [co][ci][kh][kw] -> bf16 [khw][co][ci] with the ci-chunk
// XOR-swizzle ((ci>>3)^(co&7)) pre-applied so conv2's LDS copy is linear.
// ---------------------------------------------------------------------------
__global__ __launch_bounds__(256)
void w2_pack(const float* __restrict__ w2, unsigned short* __restrict__ wB)
{
  int i = blockIdx.x*256 + threadIdx.x;   // 9*64*64 = 36864
  if (i < 36864) {
    int khw = i >> 12, rem = i & 4095, co = rem >> 6, ci = rem & 63;
    int chunk = (ci >> 3) ^ (co & 7);
    wB[khw*4096 + co*64 + chunk*8 + (ci & 7)] = f2bf(w2[co*576 + ci*9 + khw]);
  }
}

// ---------------------------------------------------------------------------
// Qw pack: fp32 [100][4196] (first 4096 cols) -> bf16 [112][4096],
// rows 100..111 zeroed (N padded to 7x16 MFMA tiles).
// ---------------------------------------------------------------------------
__global__ __launch_bounds__(256)
void qw_pack(const float* __restrict__ Qw, unsigned short* __restrict__ qB)
{
  int i = blockIdx.x*256 + threadIdx.x;   // 112*4096 = 458752
  if (i < 458752) {
    int j = i >> 12, k = i & 4095;
    qB[i] = (j < 100) ? f2bf(Qw[j*4196 + k]) : (unsigned short)0;
  }
}

// ---------------------------------------------------------------------------
// conv2 via MFMA implicit GEMM. grid 1024 (one image), block 256 (4 waves).
// Staging FUSES conv1's BN affine + ReLU. Pooled raw outputs stored bf16.
// ---------------------------------------------------------------------------
__global__ __launch_bounds__(256)
void conv2_mfma(const unsigned short* __restrict__ pmax1,
                const unsigned short* __restrict__ pmin1,
                const float* __restrict__ bn1,
                const unsigned short* __restrict__ wB,
                float* __restrict__ part,
                unsigned short* __restrict__ pmax2, unsigned short* __restrict__ pmin2)
{
  __shared__ unsigned short xin[324*64];   // 41472 B
  __shared__ unsigned short wL[9*64*64];   // 73728 B
  __shared__ float wred[4][4][16][2];      // 2 KB
  __shared__ float bnL[128];
  const int n = blockIdx.x, tid = threadIdx.x;
  const int w = tid >> 6, lane = tid & 63;
  const int q = lane >> 4, col = lane & 15;

  if (tid < 128) bnL[tid] = bn1[tid];
  // ---- stage weights (linear copy; swizzle pre-applied by w2_pack) ----
  {
    const s8v* src = (const s8v*)wB;
    s8v* dst = (s8v*)wL;
    #pragma unroll
    for (int i = 0; i < 18; ++i) dst[tid + (i<<8)] = src[tid + (i<<8)];
  }
  __syncthreads();   // bnL ready
  // ---- stage input 18x18x64 bf16 = relu(affine(pooled conv1)), halo zeros,
  //      swizzled 16B chunks ----
  {
    #pragma unroll
    for (int k = 0; k < 11; ++k) {
      int i = tid + (k<<8);
      if (i < 324*8) {
        int L = i >> 3, s = i & 7;
        int y = L / 18, x = L - y*18;
        s8v v = (s8v){0,0,0,0,0,0,0,0};
        if (y >= 1 && y <= 16 && x >= 1 && x <= 16) {
          int idx = (((n<<8) + ((y-1)<<4) + (x-1))<<6) + (s<<3);
          s8v mx = *(const s8v*)&pmax1[idx];
          s8v mn = *(const s8v*)&pmin1[idx];
          #pragma unroll
          for (int e = 0; e < 8; ++e) {
            int ci = (s<<3) + e;
            float sc = bnL[ci], sh = bnL[64+ci];
            float vv = bf2f((unsigned short)(sc >= 0.f ? mx[e] : mn[e]));
            v[e] = (short)f2bf(fmaxf(fmaf(vv, sc, sh), 0.f));
          }
        }
        *(s8v*)((char*)xin + L*128 + (((s ^ (L & 7)) << 4))) = v;
      }
    }
  }
  __syncthreads();

  f32x4 acc[4][4];   // [mtile][ntile]
  #pragma unroll
  for (int mt = 0; mt < 4; ++mt)
    #pragma unroll
    for (int t = 0; t < 4; ++t)
      acc[mt][t] = (f32x4){0.f,0.f,0.f,0.f};

  const int py0 = w << 2;   // wave's 4 image rows
  #pragma unroll 1
  for (int khw = 0; khw < 9; ++khw) {
    const int kh = khw / 3, kw = khw - 3*kh;
    const char* wslice = (const char*)wL + khw*8192;
    #pragma unroll
    for (int ks = 0; ks < 2; ++ks) {       // ci0 = 32*ks
      const int chunk = (ks << 2) + q;     // 16B-chunk of k within line
      s8v bfrag[4];
      #pragma unroll
      for (int t = 0; t < 4; ++t) {
        int co = (t << 4) + col;
        bfrag[t] = *(const s8v*)(wslice + co*128 + (((chunk ^ (co & 7)) << 4)));
      }
      #pragma unroll
      for (int mt = 0; mt < 4; ++mt) {
        int L = (py0 + mt + kh)*18 + (col + kw);
        s8v afrag = *(const s8v*)((const char*)xin + L*128 + (((chunk ^ (L & 7)) << 4)));
        #pragma unroll
        for (int t = 0; t < 4; ++t)
          acc[mt][t] = __builtin_amdgcn_mfma_f32_16x16x32_bf16(afrag, bfrag[t], acc[mt][t], 0, 0, 0);
      }
    }
  }

  // ---- stats: per-channel sum / sumsq over this block's 256 pixels ----
  #pragma unroll
  for (int t = 0; t < 4; ++t) {
    float s = 0.f, ss = 0.f;
    #pragma unroll
    for (int mt = 0; mt < 4; ++mt)
      #pragma unroll
      for (int r = 0; r < 4; ++r) {
        float v = acc[mt][t][r];
        s += v; ss = fmaf(v, v, ss);
      }
    s  += __shfl_xor(s, 16);  s  += __shfl_xor(s, 32);
    ss += __shfl_xor(ss, 16); ss += __shfl_xor(ss, 32);
    if (q == 0) { wred[w][t][col][0] = s; wred[w][t][col][1] = ss; }
  }
  __syncthreads();
  if (tid < 64) {
    float s = 0.f, ss = 0.f;
    #pragma unroll
    for (int wv = 0; wv < 4; ++wv) {
      s  += wred[wv][tid >> 4][tid & 15][0];
      ss += wred[wv][tid >> 4][tid & 15][1];
    }
    part[tid*2048 + n*2]     = s;
    part[tid*2048 + n*2 + 1] = ss;
  }

  // ---- 2x2 pooled max AND min of raw conv (affine applied later), bf16 ----
  #pragma unroll
  for (int t = 0; t < 4; ++t) {
    int co = (t << 4) + col;
    #pragma unroll
    for (int mp = 0; mp < 2; ++mp) {          // vertical pair (rows 2mp,2mp+1)
      f32x4 a0 = acc[2*mp][t], a1 = acc[2*mp+1][t];
      float mx0 = fmaxf(fmaxf(a0[0], a0[1]), fmaxf(a1[0], a1[1]));
      float mx1 = fmaxf(fmaxf(a0[2], a0[3]), fmaxf(a1[2], a1[3]));
      float mn0 = fminf(fminf(a0[0], a0[1]), fminf(a1[0], a1[1]));
      float mn1 = fminf(fminf(a0[2], a0[3]), fminf(a1[2], a1[3]));
      int pyp = (w << 1) + mp;                // pooled y
      int base = ((n*64 + co) << 6) + (pyp << 3) + (q << 1);  // feats c*64+p
      pmax2[base] = f2bf(mx0); pmax2[base+1] = f2bf(mx1);
      pmin2[base] = f2bf(mn0); pmin2[base+1] = f2bf(mn1);
    }
  }
}

// ---------------------------------------------------------------------------
// preQ partials via MFMA, fusing conv2's BN affine + ReLU into the A-frag
// load. No LDS. grid (16 mblocks x 16 ksplits), block 256.
// part layout [ks][1024][112] fp32.
// ---------------------------------------------------------------------------
__global__ __launch_bounds__(256)
void preq_mfma(const unsigned short* __restrict__ pmax2,
               const unsigned short* __restrict__ pmin2,
               const float* __restrict__ bn2,
               const unsigned short* __restrict__ qB,
               float* __restrict__ part)
{
  const int mb = blockIdx.x, ks = blockIdx.y, tid = threadIdx.x;
  const int w = tid >> 6, lane = tid & 63;
  const int q = lane >> 4, col = lane & 15;
  const int m = (mb << 6) + (w << 4) + col;    // A row this lane loads
  const int k00 = ks << 8;

  f32x4 acc[7];
  #pragma unroll
  for (int t = 0; t < 7; ++t) acc[t] = (f32x4){0.f,0.f,0.f,0.f};

  #pragma unroll 2
  for (int kk = 0; kk < 8; ++kk) {
    const int k = k00 + (kk << 5) + (q << 3);  // 8-aligned, one c per chunk
    const int c = k >> 6;
    const float sc = bn2[c], sh = bn2[64 + c];
    s8v mx = *(const s8v*)&pmax2[m*4096 + k];
    s8v mn = *(const s8v*)&pmin2[m*4096 + k];
    s8v a;
    #pragma unroll
    for (int e = 0; e < 8; ++e) {
      float vv = bf2f((unsigned short)(sc >= 0.f ? mx[e] : mn[e]));
      a[e] = (short)f2bf(fmaxf(fmaf(vv, sc, sh), 0.f));
    }
    #pragma unroll
    for (int t = 0; t < 7; ++t) {
      s8v b = *(const s8v*)&qB[(((t << 4) + col) << 12) + k];
      acc[t] = __builtin_amdgcn_mfma_f32_16x16x32_bf16(a, b, acc[t], 0, 0, 0);
    }
  }

  // C: col=lane&15 = j16, row=4q+r = m-row within the wave's 16-row tile
  float* dst = part + ks*114688 + ((mb << 6) + (w << 4) + (q << 2))*112;
  #pragma unroll
  for (int t = 0; t < 7; ++t)
    #pragma unroll
    for (int r = 0; r < 4; ++r)
      dst[r*112 + (t << 4) + col] = acc[t][r];
}

// preQ[n][100] = sum_ks part[ks][n][j] + Qb[j].  grid 400, block 256.
__global__ __launch_bounds__(256)
void preq_reduce(const float* __restrict__ part, const float* __restrict__ Qb,
                 float* __restrict__ preQ)
{
  int idx = blockIdx.x*256 + threadIdx.x;  // 102400 exact
  if (idx < 1024*100) {
    int n = idx / 100, j = idx - n*100;
    float s = Qb[j];
    #pragma unroll
    for (int ks = 0; ks < 16; ++ks) s += part[ks*114688 + n*112 + j];
    preQ[idx] = s;
  }
}

// ---------------------------------------------------------------------------
// RNN (64 sequential steps) + head. grid 16 (one block per batch b), block 512.
// R7 structure (measured 94us; best of 6 designs). Threads tid<400: o=tid>>2
// output, q4=tid&3 k-quarter; R_w row quarter (100f) + Q_w recurrent quarter
// (25f) genuinely fit in the 128-VGPR cap. Ha in LDS.
// R13: ONLY change vs R7 = tanhf -> ftanh (exp+rcp), sigmoid via __expf.
// ---------------------------------------------------------------------------
__global__ __launch_bounds__(512, 2)
void rnn_head(const float* __restrict__ preQ, const float* __restrict__ Rw,
              const float* __restrict__ Rb, const float* __restrict__ Qw,
              const float* __restrict__ Ow, const float* __restrict__ Ob,
              const float* __restrict__ f1w, const float* __restrict__ f1b,
              const float* __restrict__ f2w, const float* __restrict__ f2b,
              float* __restrict__ out)
{
  __shared__ __align__(16) float ha[400];
  __shared__ float rt[100];
  __shared__ float qt[100];
  __shared__ float pq[6400];
  __shared__ float rb[100];
  __shared__ __align__(16) float ol[128];
  __shared__ float f1[64];
  const int b = blockIdx.x, tid = threadIdx.x;

  for (int i = tid; i < 6400; i += 512) pq[i] = preQ[b*6400 + i];
  if (tid < 100) rb[tid] = Rb[tid];
  if (tid < 400) ha[tid] = 0.f;

  const int o = tid >> 2, q4 = tid & 3;
  float rw[100], qw[25];
  if (tid < 400) {
    const float* rsrc = &Rw[o*400 + q4*100];
    #pragma unroll
    for (int i = 0; i < 25; ++i) {
      float4 v = *(const float4*)&rsrc[i*4];
      rw[i*4] = v.x; rw[i*4+1] = v.y; rw[i*4+2] = v.z; rw[i*4+3] = v.w;
    }
    const float* qsrc = &Qw[o*4196 + 4096 + q4*25];
    #pragma unroll
    for (int i = 0; i < 25; ++i) qw[i] = qsrc[i];
  }
  const int ja = (tid < 400) ? (tid / 100) : 0;
  const int jq = tid - ja*100;
  const float Aa = (ja==0) ? 0.f : (ja==1) ? 0.25f : (ja==2) ? 0.5f : 0.95f;
  const float Ba = 1.f - Aa;
  __syncthreads();

  for (int t = 0; t < 64; ++t) {
    float racc = 0.f;
    if (tid < 400) {
      const float* hp = &ha[q4*100];
      #pragma unroll
      for (int i = 0; i < 25; ++i) {
        float4 h4 = *(const float4*)&hp[i*4];
        racc = fmaf(rw[i*4], h4.x, racc);
        racc = fmaf(rw[i*4+1], h4.y, racc);
        racc = fmaf(rw[i*4+2], h4.z, racc);
        racc = fmaf(rw[i*4+3], h4.w, racc);
      }
      racc += __shfl_xor(racc, 1);
      racc += __shfl_xor(racc, 2);
      if (q4 == 0) rt[o] = ftanh(racc + rb[o]);
    }
    __syncthreads();
    if (tid < 400) {
      float qacc = 0.f;
      const float* rp = &rt[q4*25];
      #pragma unroll
      for (int i = 0; i < 25; ++i) qacc = fmaf(qw[i], rp[i], qacc);
      qacc += __shfl_xor(qacc, 1);
      qacc += __shfl_xor(qacc, 2);
      if (q4 == 0) qt[o] = ftanh(qacc + pq[t*100 + o]);
    }
    __syncthreads();
    if (tid < 400) ha[tid] = fmaf(Aa, ha[tid], Ba*qt[jq]);
    __syncthreads();
  }

  // head: out_last = tanh(Hf @ Ow^T + Ob), 2 threads per output
  if (tid < 256) {
    const int j2 = tid >> 1, hh = tid & 1;
    const float* osrc = &Ow[j2*400 + hh*200];
    const float* hp = &ha[hh*200];
    float oacc = 0.f;
    #pragma unroll
    for (int i = 0; i < 50; ++i) {
      float4 w4 = *(const float4*)&osrc[i*4];
      float4 h4 = *(const float4*)&hp[i*4];
      oacc = fmaf(w4.x, h4.x, oacc); oacc = fmaf(w4.y, h4.y, oacc);
      oacc = fmaf(w4.z, h4.z, oacc); oacc = fmaf(w4.w, h4.w, oacc);
    }
    oacc += __shfl_xor(oacc, 1);
    if (hh == 0) ol[j2] = ftanh(oacc + Ob[j2]);
  }
  __syncthreads();
  if (tid < 64) {
    float a = 0.f;
    #pragma unroll
    for (int i = 0; i < 32; ++i) {
      float4 w4 = *(const float4*)&f1w[tid*128 + i*4];
      float4 o4 = *(const float4*)&ol[i*4];
      a = fmaf(w4.x, o4.x, a); a = fmaf(w4.y, o4.y, a);
      a = fmaf(w4.z, o4.z, a); a = fmaf(w4.w, o4.w, a);
    }
    f1[tid] = fmaxf(a + f1b[tid], 0.f);
  }
  __syncthreads();
  if (tid == 0) {
    float a = 0.f;
    for (int i = 0; i < 64; ++i) a = fmaf(f2w[i], f1[i], a);
    out[b] = __builtin_amdgcn_rcpf(1.f + __expf(-a));
  }
}

// ---------------------------------------------------------------------------
extern "C" void kernel_launch(void* const* d_in, const int* in_sizes, int n_in,
                              void* d_out, int out_size, void* d_ws, size_t ws_size,
                              hipStream_t stream) {
  (void)in_sizes; (void)n_in; (void)out_size; (void)ws_size;
  const float* x1   = (const float*)d_in[0];
  const float* x2   = (const float*)d_in[1];
  const float* c1w  = (const float*)d_in[2];
  // d_in[3] conv1_b: cancels in BN
  const float* bn1g = (const float*)d_in[4];
  const float* bn1b = (const float*)d_in[5];
  const float* c2w  = (const float*)d_in[6];
  // d_in[7] conv2_b: cancels in BN
  const float* bn2g = (const float*)d_in[8];
  const float* bn2b = (const float*)d_in[9];
  const float* Rw   = (const float*)d_in[10];
  const float* Rb   = (const float*)d_in[11];
  const float* Qw   = (const float*)d_in[12];
  const float* Qb   = (const float*)d_in[13];
  const float* Ow   = (const float*)d_in[14];
  const float* Ob   = (const float*)d_in[15];
  const float* f1w  = (const float*)d_in[16];
  const float* f1b  = (const float*)d_in[17];
  const float* f2w  = (const float*)d_in[18];
  const float* f2b  = (const float*)d_in[19];
  float* outp = (float*)d_out;

  // workspace layout (bytes); total ~90 MB
  char* wsb = (char*)d_ws;
  unsigned short* pmax1 = (unsigned short*)wsb;                 // 33,554,432 B
  unsigned short* pmin1 = (unsigned short*)(wsb + 33554432);    // 33,554,432 B
  unsigned short* pmax2 = (unsigned short*)(wsb + 67108864);    //  8,388,608 B
  unsigned short* pmin2 = (unsigned short*)(wsb + 75497472);    //  8,388,608 B
  float* part1  = (float*)(wsb + 83886080);                     // 524,288 B
  float* part2  = part1 + 131072;                               // 524,288 B
  float* bn1    = part2 + 131072;                               // 512 B
  float* bn2    = bn1 + 128;                                    // 512 B
  float* preQ   = bn2 + 128;                                    // 409,600 B
  unsigned short* wB1 = (unsigned short*)(preQ + 102400);       // 12,288 B
  unsigned short* wB2 = wB1 + 6144;                             // 73,728 B
  unsigned short* qB  = wB2 + 36864;                            // 917,504 B
  float* pqpart = (float*)(qB + 458752);                        // 7,340,032 B

  w1_pack<<<24, 256, 0, stream>>>(c1w, wB1);
  w2_pack<<<144, 256, 0, stream>>>(c2w, wB2);
  qw_pack<<<1792, 256, 0, stream>>>(Qw, qB);
  conv1_mfma<<<1024, 256, 0, stream>>>(x1, x2, wB1, part1, pmax1, pmin1);
  bn_finalize<<<64, 256, 0, stream>>>(part1, bn1g, bn1b, 1.f/1048576.f, bn1);
  conv2_mfma<<<1024, 256, 0, stream>>>(pmax1, pmin1, bn1, wB2, part2, pmax2, pmin2);
  bn_finalize<<<64, 256, 0, stream>>>(part2, bn2g, bn2b, 1.f/262144.f, bn2);
  preq_mfma<<<dim3(16,16), 256, 0, stream>>>(pmax2, pmin2, bn2, qB, pqpart);
  preq_reduce<<<400, 256, 0, stream>>>(pqpart, Qb, preQ);
  rnn_head<<<16, 512, 0, stream>>>(preQ, Rw, Rb, Qw, Ow, Ob, f1w, f1b, f2w, f2b, outp);
}

// Round 14
// 192.520 us; speedup vs baseline: 1.6148x; 1.0066x over previous
//
#include <hip/hip_runtime.h>
#include <math.h>

// Problem constants
// x: (16,64,3,32,32) x2 concat -> (1024,6,32,32)
// conv1 6->64 k3 p1 -> BN -> ReLU -> pool2 -> (1024,64,16,16)
// conv2 64->64 k3 p1 -> BN -> ReLU -> pool2 -> (1024,64,8,8) = feats (1024,4096)
// RNN T=64 steps over feats rows n=b*64+t ; head -> sigmoid (16,1)
//
// R13 history: R8-R12 RNN redesigns all lost to R7's per-batch VALU version;
// R13 (tanhf->ftanh) = 85us. R14: break serial fmaf chains (4-way acc) +
// float4 Q-phase reads (rt padded 4x28). Two changes, same structure.

typedef __attribute__((ext_vector_type(8))) short s8v;   // 8 bf16 (4 VGPRs)
typedef __attribute__((ext_vector_type(4))) float f32x4;

__device__ __forceinline__ unsigned short f2bf(float f) {
  union { float f; unsigned u; } x; x.f = f;
  return (unsigned short)((x.u + 0x7FFFu + ((x.u >> 16) & 1u)) >> 16);  // RNE
}
__device__ __forceinline__ float bf2f(unsigned short u) {
  union { unsigned u; float f; } x; x.u = ((unsigned)u) << 16; return x.f;
}
// fast tanh: 1 - 2/(e^{2x}+1); inf-safe via rcp (e=inf -> 0 -> +1; e->0 -> -1)
__device__ __forceinline__ float ftanh(float x) {
  float e = __expf(2.f * x);
  return 1.f - 2.f * __builtin_amdgcn_rcpf(e + 1.f);
}

// ---------------------------------------------------------------------------
// w1 pack: fp32 [co][ci=6][kh][kw] -> bf16 [kh][64co][32k], k = kw*6+ci,
// ZEROS at k in [18,32) -- these multiply the A-side overread garbage.
// ---------------------------------------------------------------------------
__global__ __launch_bounds__(256)
void w1_pack(const float* __restrict__ w1, unsigned short* __restrict__ wB1)
{
  int i = blockIdx.x*256 + threadIdx.x;   // 3*64*32 = 6144
  if (i < 6144) {
    int kh = i >> 11, rem = i & 2047, co = rem >> 5, k2 = rem & 31;
    unsigned short v = 0;
    if (k2 < 18) {
      int kw = k2 / 6, ci = k2 - 6*kw;
      v = f2bf(w1[co*54 + ci*9 + kh*3 + kw]);
    }
    wB1[i] = v;
  }
}

// ---------------------------------------------------------------------------
// conv1 via MFMA implicit GEMM, computed ONCE. grid 1024, block 256 (4 waves).
// Epilogue: per-channel sum/sumsq + 2x2 pooled max/min bf16 channel-last.
// ---------------------------------------------------------------------------
__global__ __launch_bounds__(256, 4)
void conv1_mfma(const float* __restrict__ x1, const float* __restrict__ x2,
                const unsigned short* __restrict__ wB1,
                float* __restrict__ part,
                unsigned short* __restrict__ pmax1, unsigned short* __restrict__ pmin1)
{
  __shared__ unsigned xin[3688];          // 34 rows x 108 dwords + 16 pad
  __shared__ float wred[4][4][16][2];
  const int n = blockIdx.x, tid = threadIdx.x;
  const int w = tid >> 6, lane = tid & 63;
  const int q = lane >> 4, r = lane & 15;

  // B fragments, whole kernel in regs: bf[kh][t], co = 16t + r, k0 = 8q
  s8v bf[3][4];
  #pragma unroll
  for (int kh = 0; kh < 3; ++kh)
    #pragma unroll
    for (int t = 0; t < 4; ++t)
      bf[kh][t] = *(const s8v*)&wB1[kh*2048 + (((t<<4)+r)<<5) + (q<<3)];

  // zero ALL of xin (incl. pad tail) -- overread garbage must be finite
  #pragma unroll
  for (int k = 0; k < 15; ++k) {
    int i = tid + (k<<8);
    if (i < 3688) xin[i] = 0;
  }
  __syncthreads();
  // interior fill: dword (y+1)*108 + (x+1)*3 + cp packs bf16{ci=2cp,2cp+1}
  #pragma unroll
  for (int k = 0; k < 12; ++k) {
    int i = tid + (k<<8);     // 0..3071
    int cp = i >> 10, p = i & 1023;
    int y = p >> 5, x = p & 31;
    float lo, hi;
    if (cp == 0)      { lo = x1[n*3072 + p];        hi = x1[n*3072 + 1024 + p]; }
    else if (cp == 1) { lo = x1[n*3072 + 2048 + p]; hi = x2[n*3072 + p];        }
    else              { lo = x2[n*3072 + 1024 + p]; hi = x2[n*3072 + 2048 + p]; }
    xin[(y+1)*108 + (x+1)*3 + cp] = (unsigned)f2bf(lo) | ((unsigned)f2bf(hi) << 16);
  }
  __syncthreads();

  float st[4], sq[4];
  #pragma unroll
  for (int t = 0; t < 4; ++t) { st[t] = 0.f; sq[t] = 0.f; }
  float pmx[4][2], pmn[4][2];

  #pragma unroll 1
  for (int xb = 0; xb < 2; ++xb) {
    const int xbase = xb << 4;
    #pragma unroll 2
    for (int j = 0; j < 8; ++j) {           // y = 8w + j
      const int y = (w << 3) + j;
      f32x4 acc[4];
      #pragma unroll
      for (int t = 0; t < 4; ++t) acc[t] = (f32x4){0.f,0.f,0.f,0.f};
      #pragma unroll
      for (int kh = 0; kh < 3; ++kh) {      // k-step == kh slice
        int dw = (y + kh)*108 + 3*(xbase + r) + (q << 2);
        union { unsigned u[4]; s8v v; } af;
        af.u[0] = xin[dw];   af.u[1] = xin[dw+1];
        af.u[2] = xin[dw+2]; af.u[3] = xin[dw+3];
        #pragma unroll
        for (int t = 0; t < 4; ++t)
          acc[t] = __builtin_amdgcn_mfma_f32_16x16x32_bf16(af.v, bf[kh][t], acc[t], 0, 0, 0);
      }
      #pragma unroll
      for (int t = 0; t < 4; ++t) {
        st[t] += acc[t][0]+acc[t][1]+acc[t][2]+acc[t][3];
        sq[t] = fmaf(acc[t][0],acc[t][0], fmaf(acc[t][1],acc[t][1],
                fmaf(acc[t][2],acc[t][2], fmaf(acc[t][3],acc[t][3], sq[t]))));
      }
      if ((j & 1) == 0) {                   // even y: stash x-pair max/min
        #pragma unroll
        for (int t = 0; t < 4; ++t) {
          pmx[t][0] = fmaxf(acc[t][0], acc[t][1]); pmx[t][1] = fmaxf(acc[t][2], acc[t][3]);
          pmn[t][0] = fminf(acc[t][0], acc[t][1]); pmn[t][1] = fminf(acc[t][2], acc[t][3]);
        }
      } else {                              // odd y: combine + write pooled
        const int py = y >> 1;
        #pragma unroll
        for (int t = 0; t < 4; ++t) {
          int co = (t << 4) + r;
          #pragma unroll
          for (int pp = 0; pp < 2; ++pp) {
            float mx = fmaxf(pmx[t][pp], fmaxf(acc[t][2*pp], acc[t][2*pp+1]));
            float mn = fminf(pmn[t][pp], fminf(acc[t][2*pp], acc[t][2*pp+1]));
            int pxp = (xb << 3) + (q << 1) + pp;
            int o = (((n << 8) + (py << 4) + pxp) << 6) + co;
            pmax1[o] = f2bf(mx);
            pmin1[o] = f2bf(mn);
          }
        }
      }
    }
  }

  #pragma unroll
  for (int t = 0; t < 4; ++t) {
    float s = st[t], ss = sq[t];
    s  += __shfl_xor(s, 16);  s  += __shfl_xor(s, 32);
    ss += __shfl_xor(ss, 16); ss += __shfl_xor(ss, 32);
    if (q == 0) { wred[w][t][r][0] = s; wred[w][t][r][1] = ss; }
  }
  __syncthreads();
  if (tid < 64) {
    float s = 0.f, ss = 0.f;
    #pragma unroll
    for (int wv = 0; wv < 4; ++wv) {
      s  += wred[wv][tid >> 4][tid & 15][0];
      ss += wred[wv][tid >> 4][tid & 15][1];
    }
    part[tid*2048 + n*2]     = s;     // layout [c][n][2]
    part[tid*2048 + n*2 + 1] = ss;
  }
}

// ---------------------------------------------------------------------------
// BN finalize: per-channel mean/var -> scale/shift.  grid 64, block 256.
// ---------------------------------------------------------------------------
__global__ __launch_bounds__(256)
void bn_finalize(const float* __restrict__ part, const float* __restrict__ g,
                 const float* __restrict__ beta, float inv_cnt, float* __restrict__ bn)
{
  __shared__ float red[8];
  const int c = blockIdx.x, tid = threadIdx.x;
  float s = 0.f, ss = 0.f;
  for (int n = tid; n < 1024; n += 256) {
    s  += part[c*2048 + n*2];
    ss += part[c*2048 + n*2 + 1];
  }
  #pragma unroll
  for (int d = 32; d; d >>= 1) { s += __shfl_xor(s, d); ss += __shfl_xor(ss, d); }
  if ((tid & 63) == 0) { red[(tid>>6)*2] = s; red[(tid>>6)*2+1] = ss; }
  __syncthreads();
  if (tid == 0) {
    float S  = red[0]+red[2]+red[4]+red[6];
    float SS = red[1]+red[3]+red[5]+red[7];
    float m  = S * inv_cnt;
    float var = SS * inv_cnt - m*m;
    float sc = g[c] * rsqrtf(var + 1e-5f);
    bn[c]    = sc;
    bn[64+c] = beta[c] - m*sc;
  }
}

// ---------------------------------------------------------------------------
// w2 pack: fp32 [co][ci][kh][kw] -> bf16 [khw][co][ci] with the ci-chunk
// XOR-swizzle ((ci>>3)^(co&7)) pre-applied so conv2's LDS copy is linear.
// ---------------------------------------------------------------------------
__global__ __launch_bounds__(256)
void w2_pack(const float* __restrict__ w2, unsigned short* __restrict__ wB)
{
  int i = blockIdx.x*256 + threadIdx.x;   // 9*64*64 = 36864
  if (i < 36864) {
    int khw = i >> 12, rem = i & 4095, co = rem >> 6, ci = rem & 63;
    int chunk = (ci >> 3) ^ (co & 7);
    wB[khw*4096 + co*64 + chunk*8 + (ci & 7)] = f2bf(w2[co*576 + ci*9 + khw]);
  }
}

// ---------------------------------------------------------------------------
// Qw pack: fp32 [100][4196] (first 4096 cols) -> bf16 [112][4096],
// rows 100..111 zeroed (N padded to 7x16 MFMA tiles).
// ---------------------------------------------------------------------------
__global__ __launch_bounds__(256)
void qw_pack(const float* __restrict__ Qw, unsigned short* __restrict__ qB)
{
  int i = blockIdx.x*256 + threadIdx.x;   // 112*4096 = 458752
  if (i < 458752) {
    int j = i >> 12, k = i & 4095;
    qB[i] = (j < 100) ? f2bf(Qw[j*4196 + k]) : (unsigned short)0;
  }
}

// ---------------------------------------------------------------------------
// conv2 via MFMA implicit GEMM. grid 1024 (one image), block 256 (4 waves).
// Staging FUSES conv1's BN affine + ReLU. Pooled raw outputs stored bf16.
// ---------------------------------------------------------------------------
__global__ __launch_bounds__(256)
void conv2_mfma(const unsigned short* __restrict__ pmax1,
                const unsigned short* __restrict__ pmin1,
                const float* __restrict__ bn1,
                const unsigned short* __restrict__ wB,
                float* __restrict__ part,
                unsigned short* __restrict__ pmax2, unsigned short* __restrict__ pmin2)
{
  __shared__ unsigned short xin[324*64];   // 41472 B
  __shared__ unsigned short wL[9*64*64];   // 73728 B
  __shared__ float wred[4][4][16][2];      // 2 KB
  __shared__ float bnL[128];
  const int n = blockIdx.x, tid = threadIdx.x;
  const int w = tid >> 6, lane = tid & 63;
  const int q = lane >> 4, col = lane & 15;

  if (tid < 128) bnL[tid] = bn1[tid];
  // ---- stage weights (linear copy; swizzle pre-applied by w2_pack) ----
  {
    const s8v* src = (const s8v*)wB;
    s8v* dst = (s8v*)wL;
    #pragma unroll
    for (int i = 0; i < 18; ++i) dst[tid + (i<<8)] = src[tid + (i<<8)];
  }
  __syncthreads();   // bnL ready
  // ---- stage input 18x18x64 bf16 = relu(affine(pooled conv1)), halo zeros,
  //      swizzled 16B chunks ----
  {
    #pragma unroll
    for (int k = 0; k < 11; ++k) {
      int i = tid + (k<<8);
      if (i < 324*8) {
        int L = i >> 3, s = i & 7;
        int y = L / 18, x = L - y*18;
        s8v v = (s8v){0,0,0,0,0,0,0,0};
        if (y >= 1 && y <= 16 && x >= 1 && x <= 16) {
          int idx = (((n<<8) + ((y-1)<<4) + (x-1))<<6) + (s<<3);
          s8v mx = *(const s8v*)&pmax1[idx];
          s8v mn = *(const s8v*)&pmin1[idx];
          #pragma unroll
          for (int e = 0; e < 8; ++e) {
            int ci = (s<<3) + e;
            float sc = bnL[ci], sh = bnL[64+ci];
            float vv = bf2f((unsigned short)(sc >= 0.f ? mx[e] : mn[e]));
            v[e] = (short)f2bf(fmaxf(fmaf(vv, sc, sh), 0.f));
          }
        }
        *(s8v*)((char*)xin + L*128 + (((s ^ (L & 7)) << 4))) = v;
      }
    }
  }
  __syncthreads();

  f32x4 acc[4][4];   // [mtile][ntile]
  #pragma unroll
  for (int mt = 0; mt < 4; ++mt)
    #pragma unroll
    for (int t = 0; t < 4; ++t)
      acc[mt][t] = (f32x4){0.f,0.f,0.f,0.f};

  const int py0 = w << 2;   // wave's 4 image rows
  #pragma unroll 1
  for (int khw = 0; khw < 9; ++khw) {
    const int kh = khw / 3, kw = khw - 3*kh;
    const char* wslice = (const char*)wL + khw*8192;
    #pragma unroll
    for (int ks = 0; ks < 2; ++ks) {       // ci0 = 32*ks
      const int chunk = (ks << 2) + q;     // 16B-chunk of k within line
      s8v bfrag[4];
      #pragma unroll
      for (int t = 0; t < 4; ++t) {
        int co = (t << 4) + col;
        bfrag[t] = *(const s8v*)(wslice + co*128 + (((chunk ^ (co & 7)) << 4)));
      }
      #pragma unroll
      for (int mt = 0; mt < 4; ++mt) {
        int L = (py0 + mt + kh)*18 + (col + kw);
        s8v afrag = *(const s8v*)((const char*)xin + L*128 + (((chunk ^ (L & 7)) << 4)));
        #pragma unroll
        for (int t = 0; t < 4; ++t)
          acc[mt][t] = __builtin_amdgcn_mfma_f32_16x16x32_bf16(afrag, bfrag[t], acc[mt][t], 0, 0, 0);
      }
    }
  }

  // ---- stats: per-channel sum / sumsq over this block's 256 pixels ----
  #pragma unroll
  for (int t = 0; t < 4; ++t) {
    float s = 0.f, ss = 0.f;
    #pragma unroll
    for (int mt = 0; mt < 4; ++mt)
      #pragma unroll
      for (int r = 0; r < 4; ++r) {
        float v = acc[mt][t][r];
        s += v; ss = fmaf(v, v, ss);
      }
    s  += __shfl_xor(s, 16);  s  += __shfl_xor(s, 32);
    ss += __shfl_xor(ss, 16); ss += __shfl_xor(ss, 32);
    if (q == 0) { wred[w][t][col][0] = s; wred[w][t][col][1] = ss; }
  }
  __syncthreads();
  if (tid < 64) {
    float s = 0.f, ss = 0.f;
    #pragma unroll
    for (int wv = 0; wv < 4; ++wv) {
      s  += wred[wv][tid >> 4][tid & 15][0];
      ss += wred[wv][tid >> 4][tid & 15][1];
    }
    part[tid*2048 + n*2]     = s;
    part[tid*2048 + n*2 + 1] = ss;
  }

  // ---- 2x2 pooled max AND min of raw conv (affine applied later), bf16 ----
  #pragma unroll
  for (int t = 0; t < 4; ++t) {
    int co = (t << 4) + col;
    #pragma unroll
    for (int mp = 0; mp < 2; ++mp) {          // vertical pair (rows 2mp,2mp+1)
      f32x4 a0 = acc[2*mp][t], a1 = acc[2*mp+1][t];
      float mx0 = fmaxf(fmaxf(a0[0], a0[1]), fmaxf(a1[0], a1[1]));
      float mx1 = fmaxf(fmaxf(a0[2], a0[3]), fmaxf(a1[2], a1[3]));
      float mn0 = fminf(fminf(a0[0], a0[1]), fminf(a1[0], a1[1]));
      float mn1 = fminf(fminf(a0[2], a0[3]), fminf(a1[2], a1[3]));
      int pyp = (w << 1) + mp;                // pooled y
      int base = ((n*64 + co) << 6) + (pyp << 3) + (q << 1);  // feats c*64+p
      pmax2[base] = f2bf(mx0); pmax2[base+1] = f2bf(mx1);
      pmin2[base] = f2bf(mn0); pmin2[base+1] = f2bf(mn1);
    }
  }
}

// ---------------------------------------------------------------------------
// preQ partials via MFMA, fusing conv2's BN affine + ReLU into the A-frag
// load. No LDS. grid (16 mblocks x 16 ksplits), block 256.
// part layout [ks][1024][112] fp32.
// ---------------------------------------------------------------------------
__global__ __launch_bounds__(256)
void preq_mfma(const unsigned short* __restrict__ pmax2,
               const unsigned short* __restrict__ pmin2,
               const float* __restrict__ bn2,
               const unsigned short* __restrict__ qB,
               float* __restrict__ part)
{
  const int mb = blockIdx.x, ks = blockIdx.y, tid = threadIdx.x;
  const int w = tid >> 6, lane = tid & 63;
  const int q = lane >> 4, col = lane & 15;
  const int m = (mb << 6) + (w << 4) + col;    // A row this lane loads
  const int k00 = ks << 8;

  f32x4 acc[7];
  #pragma unroll
  for (int t = 0; t < 7; ++t) acc[t] = (f32x4){0.f,0.f,0.f,0.f};

  #pragma unroll 2
  for (int kk = 0; kk < 8; ++kk) {
    const int k = k00 + (kk << 5) + (q << 3);  // 8-aligned, one c per chunk
    const int c = k >> 6;
    const float sc = bn2[c], sh = bn2[64 + c];
    s8v mx = *(const s8v*)&pmax2[m*4096 + k];
    s8v mn = *(const s8v*)&pmin2[m*4096 + k];
    s8v a;
    #pragma unroll
    for (int e = 0; e < 8; ++e) {
      float vv = bf2f((unsigned short)(sc >= 0.f ? mx[e] : mn[e]));
      a[e] = (short)f2bf(fmaxf(fmaf(vv, sc, sh), 0.f));
    }
    #pragma unroll
    for (int t = 0; t < 7; ++t) {
      s8v b = *(const s8v*)&qB[(((t << 4) + col) << 12) + k];
      acc[t] = __builtin_amdgcn_mfma_f32_16x16x32_bf16(a, b, acc[t], 0, 0, 0);
    }
  }

  // C: col=lane&15 = j16, row=4q+r = m-row within the wave's 16-row tile
  float* dst = part + ks*114688 + ((mb << 6) + (w << 4) + (q << 2))*112;
  #pragma unroll
  for (int t = 0; t < 7; ++t)
    #pragma unroll
    for (int r = 0; r < 4; ++r)
      dst[r*112 + (t << 4) + col] = acc[t][r];
}

// preQ[n][100] = sum_ks part[ks][n][j] + Qb[j].  grid 400, block 256.
__global__ __launch_bounds__(256)
void preq_reduce(const float* __restrict__ part, const float* __restrict__ Qb,
                 float* __restrict__ preQ)
{
  int idx = blockIdx.x*256 + threadIdx.x;  // 102400 exact
  if (idx < 1024*100) {
    int n = idx / 100, j = idx - n*100;
    float s = Qb[j];
    #pragma unroll
    for (int ks = 0; ks < 16; ++ks) s += part[ks*114688 + n*112 + j];
    preQ[idx] = s;
  }
}

// ---------------------------------------------------------------------------
// RNN (64 sequential steps) + head. grid 16 (one block per batch b), block 512.
// R7 structure. R14 changes (two, controlled):
//  1. R-phase racc -> 4 independent accumulators (fmaf dep chain 100 -> 25);
//     Q-phase -> 2 accumulators.
//  2. rt stored padded 4x28 floats (quarters 16B-aligned) -> Q-phase reads
//     7x ds_read_b128 instead of 25x ds_read_b32; qw padded to 28 w/ zeros.
// ---------------------------------------------------------------------------
__global__ __launch_bounds__(512, 2)
void rnn_head(const float* __restrict__ preQ, const float* __restrict__ Rw,
              const float* __restrict__ Rb, const float* __restrict__ Qw,
              const float* __restrict__ Ow, const float* __restrict__ Ob,
              const float* __restrict__ f1w, const float* __restrict__ f1b,
              const float* __restrict__ f2w, const float* __restrict__ f2b,
              float* __restrict__ out)
{
  __shared__ __align__(16) float ha[400];
  __shared__ __align__(16) float rtP[112];   // 4 quarters x 28 (pads zero)
  __shared__ float qt[100];
  __shared__ float pq[6400];
  __shared__ float rb[100];
  __shared__ __align__(16) float ol[128];
  __shared__ float f1[64];
  const int b = blockIdx.x, tid = threadIdx.x;

  for (int i = tid; i < 6400; i += 512) pq[i] = preQ[b*6400 + i];
  if (tid < 100) rb[tid] = Rb[tid];
  if (tid < 400) ha[tid] = 0.f;
  if (tid < 112) rtP[tid] = 0.f;             // pads stay zero forever

  const int o = tid >> 2, q4 = tid & 3;
  // rt write slot for thread (o, q4==0): quarter o/25, element o%25
  const int rtSlot = (o / 25)*28 + (o % 25);
  float rw[100], qw[28];
  if (tid < 400) {
    const float* rsrc = &Rw[o*400 + q4*100];
    #pragma unroll
    for (int i = 0; i < 25; ++i) {
      float4 v = *(const float4*)&rsrc[i*4];
      rw[i*4] = v.x; rw[i*4+1] = v.y; rw[i*4+2] = v.z; rw[i*4+3] = v.w;
    }
    const float* qsrc = &Qw[o*4196 + 4096 + q4*25];
    #pragma unroll
    for (int i = 0; i < 25; ++i) qw[i] = qsrc[i];
    qw[25] = 0.f; qw[26] = 0.f; qw[27] = 0.f;   // multiply rtP pads
  }
  const int ja = (tid < 400) ? (tid / 100) : 0;
  const int jq = tid - ja*100;
  const float Aa = (ja==0) ? 0.f : (ja==1) ? 0.25f : (ja==2) ? 0.5f : 0.95f;
  const float Ba = 1.f - Aa;
  __syncthreads();

  for (int t = 0; t < 64; ++t) {
    if (tid < 400) {
      // R: 4 independent fmaf chains over the 100-wide quarter
      float r0 = 0.f, r1 = 0.f, r2 = 0.f, r3 = 0.f;
      const float* hp = &ha[q4*100];
      #pragma unroll
      for (int i = 0; i < 25; i += 4) {
        float4 a0 = *(const float4*)&hp[i*4];
        float4 a1 = *(const float4*)&hp[i*4+4];
        float4 a2 = *(const float4*)&hp[i*4+8];
        float4 a3 = *(const float4*)&hp[i*4+12];
        r0 = fmaf(rw[i*4],    a0.x, r0); r0 = fmaf(rw[i*4+1],  a0.y, r0);
        r0 = fmaf(rw[i*4+2],  a0.z, r0); r0 = fmaf(rw[i*4+3],  a0.w, r0);
        if (i+1 < 25) {
          r1 = fmaf(rw[i*4+4],  a1.x, r1); r1 = fmaf(rw[i*4+5],  a1.y, r1);
          r1 = fmaf(rw[i*4+6],  a1.z, r1); r1 = fmaf(rw[i*4+7],  a1.w, r1);
        }
        if (i+2 < 25) {
          r2 = fmaf(rw[i*4+8],  a2.x, r2); r2 = fmaf(rw[i*4+9],  a2.y, r2);
          r2 = fmaf(rw[i*4+10], a2.z, r2); r2 = fmaf(rw[i*4+11], a2.w, r2);
        }
        if (i+3 < 25) {
          r3 = fmaf(rw[i*4+12], a3.x, r3); r3 = fmaf(rw[i*4+13], a3.y, r3);
          r3 = fmaf(rw[i*4+14], a3.z, r3); r3 = fmaf(rw[i*4+15], a3.w, r3);
        }
      }
      float racc = (r0 + r1) + (r2 + r3);
      racc += __shfl_xor(racc, 1);
      racc += __shfl_xor(racc, 2);
      if (q4 == 0) rtP[rtSlot] = ftanh(racc + rb[o]);
    }
    __syncthreads();
    if (tid < 400) {
      // Q: 7 float4 reads of the padded quarter, 2 chains
      float s0 = 0.f, s1 = 0.f;
      const float* rp = &rtP[q4*28];
      #pragma unroll
      for (int i = 0; i < 7; i += 2) {
        float4 v0 = *(const float4*)&rp[i*4];
        s0 = fmaf(qw[i*4],   v0.x, s0); s0 = fmaf(qw[i*4+1], v0.y, s0);
        s0 = fmaf(qw[i*4+2], v0.z, s0); s0 = fmaf(qw[i*4+3], v0.w, s0);
        if (i+1 < 7) {
          float4 v1 = *(const float4*)&rp[i*4+4];
          s1 = fmaf(qw[i*4+4], v1.x, s1); s1 = fmaf(qw[i*4+5], v1.y, s1);
          s1 = fmaf(qw[i*4+6], v1.z, s1); s1 = fmaf(qw[i*4+7], v1.w, s1);
        }
      }
      float qacc = s0 + s1;
      qacc += __shfl_xor(qacc, 1);
      qacc += __shfl_xor(qacc, 2);
      if (q4 == 0) qt[o] = ftanh(qacc + pq[t*100 + o]);
    }
    __syncthreads();
    if (tid < 400) ha[tid] = fmaf(Aa, ha[tid], Ba*qt[jq]);
    __syncthreads();
  }

  // head: out_last = tanh(Hf @ Ow^T + Ob), 2 threads per output
  if (tid < 256) {
    const int j2 = tid >> 1, hh = tid & 1;
    const float* osrc = &Ow[j2*400 + hh*200];
    const float* hp = &ha[hh*200];
    float oacc = 0.f;
    #pragma unroll
    for (int i = 0; i < 50; ++i) {
      float4 w4 = *(const float4*)&osrc[i*4];
      float4 h4 = *(const float4*)&hp[i*4];
      oacc = fmaf(w4.x, h4.x, oacc); oacc = fmaf(w4.y, h4.y, oacc);
      oacc = fmaf(w4.z, h4.z, oacc); oacc = fmaf(w4.w, h4.w, oacc);
    }
    oacc += __shfl_xor(oacc, 1);
    if (hh == 0) ol[j2] = ftanh(oacc + Ob[j2]);
  }
  __syncthreads();
  if (tid < 64) {
    float a = 0.f;
    #pragma unroll
    for (int i = 0; i < 32; ++i) {
      float4 w4 = *(const float4*)&f1w[tid*128 + i*4];
      float4 o4 = *(const float4*)&ol[i*4];
      a = fmaf(w4.x, o4.x, a); a = fmaf(w4.y, o4.y, a);
      a = fmaf(w4.z, o4.z, a); a = fmaf(w4.w, o4.w, a);
    }
    f1[tid] = fmaxf(a + f1b[tid], 0.f);
  }
  __syncthreads();
  if (tid == 0) {
    float a = 0.f;
    for (int i = 0; i < 64; ++i) a = fmaf(f2w[i], f1[i], a);
    out[b] = __builtin_amdgcn_rcpf(1.f + __expf(-a));
  }
}

// ---------------------------------------------------------------------------
extern "C" void kernel_launch(void* const* d_in, const int* in_sizes, int n_in,
                              void* d_out, int out_size, void* d_ws, size_t ws_size,
                              hipStream_t stream) {
  (void)in_sizes; (void)n_in; (void)out_size; (void)ws_size;
  const float* x1   = (const float*)d_in[0];
  const float* x2   = (const float*)d_in[1];
  const float* c1w  = (const float*)d_in[2];
  // d_in[3] conv1_b: cancels in BN
  const float* bn1g = (const float*)d_in[4];
  const float* bn1b = (const float*)d_in[5];
  const float* c2w  = (const float*)d_in[6];
  // d_in[7] conv2_b: cancels in BN
  const float* bn2g = (const float*)d_in[8];
  const float* bn2b = (const float*)d_in[9];
  const float* Rw   = (const float*)d_in[10];
  const float* Rb   = (const float*)d_in[11];
  const float* Qw   = (const float*)d_in[12];
  const float* Qb   = (const float*)d_in[13];
  const float* Ow   = (const float*)d_in[14];
  const float* Ob   = (const float*)d_in[15];
  const float* f1w  = (const float*)d_in[16];
  const float* f1b  = (const float*)d_in[17];
  const float* f2w  = (const float*)d_in[18];
  const float* f2b  = (const float*)d_in[19];
  float* outp = (float*)d_out;

  // workspace layout (bytes); total ~90 MB
  char* wsb = (char*)d_ws;
  unsigned short* pmax1 = (unsigned short*)wsb;                 // 33,554,432 B
  unsigned short* pmin1 = (unsigned short*)(wsb + 33554432);    // 33,554,432 B
  unsigned short* pmax2 = (unsigned short*)(wsb + 67108864);    //  8,388,608 B
  unsigned short* pmin2 = (unsigned short*)(wsb + 75497472);    //  8,388,608 B
  float* part1  = (float*)(wsb + 83886080);                     // 524,288 B
  float* part2  = part1 + 131072;                               // 524,288 B
  float* bn1    = part2 + 131072;                               // 512 B
  float* bn2    = bn1 + 128;                                    // 512 B
  float* preQ   = bn2 + 128;                                    // 409,600 B
  unsigned short* wB1 = (unsigned short*)(preQ + 102400);       // 12,288 B
  unsigned short* wB2 = wB1 + 6144;                             // 73,728 B
  unsigned short* qB  = wB2 + 36864;                            // 917,504 B
  float* pqpart = (float*)(qB + 458752);                        // 7,340,032 B

  w1_pack<<<24, 256, 0, stream>>>(c1w, wB1);
  w2_pack<<<144, 256, 0, stream>>>(c2w, wB2);
  qw_pack<<<1792, 256, 0, stream>>>(Qw, qB);
  conv1_mfma<<<1024, 256, 0, stream>>>(x1, x2, wB1, part1, pmax1, pmin1);
  bn_finalize<<<64, 256, 0, stream>>>(part1, bn1g, bn1b, 1.f/1048576.f, bn1);
  conv2_mfma<<<1024, 256, 0, stream>>>(pmax1, pmin1, bn1, wB2, part2, pmax2, pmin2);
  bn_finalize<<<64, 256, 0, stream>>>(part2, bn2g, bn2b, 1.f/262144.f, bn2);
  preq_mfma<<<dim3(16,16), 256, 0, stream>>>(pmax2, pmin2, bn2, qB, pqpart);
  preq_reduce<<<400, 256, 0, stream>>>(pqpart, Qb, preQ);
  rnn_head<<<16, 512, 0, stream>>>(preQ, Rw, Rb, Qw, Ow, Ob, f1w, f1b, f2w, f2b, outp);
}

// Round 15
// 186.591 us; speedup vs baseline: 1.6661x; 1.0318x over previous
//
#include <hip/hip_runtime.h>
#include <math.h>

// Problem constants
// x: (16,64,3,32,32) x2 concat -> (1024,6,32,32)
// conv1 6->64 k3 p1 -> BN -> ReLU -> pool2 -> (1024,64,16,16)
// conv2 64->64 k3 p1 -> BN -> ReLU -> pool2 -> (1024,64,8,8) = feats (1024,4096)
// RNN T=64 steps over feats rows n=b*64+t ; head -> sigmoid (16,1)
//
// RNN history: R8-R12 redesigns lost to R7's per-batch VALU loop; R13 ftanh
// 94->85us; R14 ILP+b128 85->82us (stall-bound, not VALU/LDS-width). R15:
// fuse Ha-update into Q-phase (all 4 quad threads have qacc post-shfl ->
// redundant qt; Ha element lives in a REGISTER, write-through to LDS) ->
// 2 barriers/step, qt[] array and update-phase LDS reads deleted.

typedef __attribute__((ext_vector_type(8))) short s8v;   // 8 bf16 (4 VGPRs)
typedef __attribute__((ext_vector_type(4))) float f32x4;

__device__ __forceinline__ unsigned short f2bf(float f) {
  union { float f; unsigned u; } x; x.f = f;
  return (unsigned short)((x.u + 0x7FFFu + ((x.u >> 16) & 1u)) >> 16);  // RNE
}
__device__ __forceinline__ float bf2f(unsigned short u) {
  union { unsigned u; float f; } x; x.u = ((unsigned)u) << 16; return x.f;
}
// fast tanh: 1 - 2/(e^{2x}+1); inf-safe via rcp (e=inf -> 0 -> +1; e->0 -> -1)
__device__ __forceinline__ float ftanh(float x) {
  float e = __expf(2.f * x);
  return 1.f - 2.f * __builtin_amdgcn_rcpf(e + 1.f);
}

// ---------------------------------------------------------------------------
// w1 pack: fp32 [co][ci=6][kh][kw] -> bf16 [kh][64co][32k], k = kw*6+ci,
// ZEROS at k in [18,32) -- these multiply the A-side overread garbage.
// ---------------------------------------------------------------------------
__global__ __launch_bounds__(256)
void w1_pack(const float* __restrict__ w1, unsigned short* __restrict__ wB1)
{
  int i = blockIdx.x*256 + threadIdx.x;   // 3*64*32 = 6144
  if (i < 6144) {
    int kh = i >> 11, rem = i & 2047, co = rem >> 5, k2 = rem & 31;
    unsigned short v = 0;
    if (k2 < 18) {
      int kw = k2 / 6, ci = k2 - 6*kw;
      v = f2bf(w1[co*54 + ci*9 + kh*3 + kw]);
    }
    wB1[i] = v;
  }
}

// ---------------------------------------------------------------------------
// conv1 via MFMA implicit GEMM, computed ONCE. grid 1024, block 256 (4 waves).
// Epilogue: per-channel sum/sumsq + 2x2 pooled max/min bf16 channel-last.
// ---------------------------------------------------------------------------
__global__ __launch_bounds__(256, 4)
void conv1_mfma(const float* __restrict__ x1, const float* __restrict__ x2,
                const unsigned short* __restrict__ wB1,
                float* __restrict__ part,
                unsigned short* __restrict__ pmax1, unsigned short* __restrict__ pmin1)
{
  __shared__ unsigned xin[3688];          // 34 rows x 108 dwords + 16 pad
  __shared__ float wred[4][4][16][2];
  const int n = blockIdx.x, tid = threadIdx.x;
  const int w = tid >> 6, lane = tid & 63;
  const int q = lane >> 4, r = lane & 15;

  // B fragments, whole kernel in regs: bf[kh][t], co = 16t + r, k0 = 8q
  s8v bf[3][4];
  #pragma unroll
  for (int kh = 0; kh < 3; ++kh)
    #pragma unroll
    for (int t = 0; t < 4; ++t)
      bf[kh][t] = *(const s8v*)&wB1[kh*2048 + (((t<<4)+r)<<5) + (q<<3)];

  // zero ALL of xin (incl. pad tail) -- overread garbage must be finite
  #pragma unroll
  for (int k = 0; k < 15; ++k) {
    int i = tid + (k<<8);
    if (i < 3688) xin[i] = 0;
  }
  __syncthreads();
  // interior fill: dword (y+1)*108 + (x+1)*3 + cp packs bf16{ci=2cp,2cp+1}
  #pragma unroll
  for (int k = 0; k < 12; ++k) {
    int i = tid + (k<<8);     // 0..3071
    int cp = i >> 10, p = i & 1023;
    int y = p >> 5, x = p & 31;
    float lo, hi;
    if (cp == 0)      { lo = x1[n*3072 + p];        hi = x1[n*3072 + 1024 + p]; }
    else if (cp == 1) { lo = x1[n*3072 + 2048 + p]; hi = x2[n*3072 + p];        }
    else              { lo = x2[n*3072 + 1024 + p]; hi = x2[n*3072 + 2048 + p]; }
    xin[(y+1)*108 + (x+1)*3 + cp] = (unsigned)f2bf(lo) | ((unsigned)f2bf(hi) << 16);
  }
  __syncthreads();

  float st[4], sq[4];
  #pragma unroll
  for (int t = 0; t < 4; ++t) { st[t] = 0.f; sq[t] = 0.f; }
  float pmx[4][2], pmn[4][2];

  #pragma unroll 1
  for (int xb = 0; xb < 2; ++xb) {
    const int xbase = xb << 4;
    #pragma unroll 2
    for (int j = 0; j < 8; ++j) {           // y = 8w + j
      const int y = (w << 3) + j;
      f32x4 acc[4];
      #pragma unroll
      for (int t = 0; t < 4; ++t) acc[t] = (f32x4){0.f,0.f,0.f,0.f};
      #pragma unroll
      for (int kh = 0; kh < 3; ++kh) {      // k-step == kh slice
        int dw = (y + kh)*108 + 3*(xbase + r) + (q << 2);
        union { unsigned u[4]; s8v v; } af;
        af.u[0] = xin[dw];   af.u[1] = xin[dw+1];
        af.u[2] = xin[dw+2]; af.u[3] = xin[dw+3];
        #pragma unroll
        for (int t = 0; t < 4; ++t)
          acc[t] = __builtin_amdgcn_mfma_f32_16x16x32_bf16(af.v, bf[kh][t], acc[t], 0, 0, 0);
      }
      #pragma unroll
      for (int t = 0; t < 4; ++t) {
        st[t] += acc[t][0]+acc[t][1]+acc[t][2]+acc[t][3];
        sq[t] = fmaf(acc[t][0],acc[t][0], fmaf(acc[t][1],acc[t][1],
                fmaf(acc[t][2],acc[t][2], fmaf(acc[t][3],acc[t][3], sq[t]))));
      }
      if ((j & 1) == 0) {                   // even y: stash x-pair max/min
        #pragma unroll
        for (int t = 0; t < 4; ++t) {
          pmx[t][0] = fmaxf(acc[t][0], acc[t][1]); pmx[t][1] = fmaxf(acc[t][2], acc[t][3]);
          pmn[t][0] = fminf(acc[t][0], acc[t][1]); pmn[t][1] = fminf(acc[t][2], acc[t][3]);
        }
      } else {                              // odd y: combine + write pooled
        const int py = y >> 1;
        #pragma unroll
        for (int t = 0; t < 4; ++t) {
          int co = (t << 4) + r;
          #pragma unroll
          for (int pp = 0; pp < 2; ++pp) {
            float mx = fmaxf(pmx[t][pp], fmaxf(acc[t][2*pp], acc[t][2*pp+1]));
            float mn = fminf(pmn[t][pp], fminf(acc[t][2*pp], acc[t][2*pp+1]));
            int pxp = (xb << 3) + (q << 1) + pp;
            int o = (((n << 8) + (py << 4) + pxp) << 6) + co;
            pmax1[o] = f2bf(mx);
            pmin1[o] = f2bf(mn);
          }
        }
      }
    }
  }

  #pragma unroll
  for (int t = 0; t < 4; ++t) {
    float s = st[t], ss = sq[t];
    s  += __shfl_xor(s, 16);  s  += __shfl_xor(s, 32);
    ss += __shfl_xor(ss, 16); ss += __shfl_xor(ss, 32);
    if (q == 0) { wred[w][t][r][0] = s; wred[w][t][r][1] = ss; }
  }
  __syncthreads();
  if (tid < 64) {
    float s = 0.f, ss = 0.f;
    #pragma unroll
    for (int wv = 0; wv < 4; ++wv) {
      s  += wred[wv][tid >> 4][tid & 15][0];
      ss += wred[wv][tid >> 4][tid & 15][1];
    }
    part[tid*2048 + n*2]     = s;     // layout [c][n][2]
    part[tid*2048 + n*2 + 1] = ss;
  }
}

// ---------------------------------------------------------------------------
// BN finalize: per-channel mean/var -> scale/shift.  grid 64, block 256.
// ---------------------------------------------------------------------------
__global__ __launch_bounds__(256)
void bn_finalize(const float* __restrict__ part, const float* __restrict__ g,
                 const float* __restrict__ beta, float inv_cnt, float* __restrict__ bn)
{
  __shared__ float red[8];
  const int c = blockIdx.x, tid = threadIdx.x;
  float s = 0.f, ss = 0.f;
  for (int n = tid; n < 1024; n += 256) {
    s  += part[c*2048 + n*2];
    ss += part[c*2048 + n*2 + 1];
  }
  #pragma unroll
  for (int d = 32; d; d >>= 1) { s += __shfl_xor(s, d); ss += __shfl_xor(ss, d); }
  if ((tid & 63) == 0) { red[(tid>>6)*2] = s; red[(tid>>6)*2+1] = ss; }
  __syncthreads();
  if (tid == 0) {
    float S  = red[0]+red[2]+red[4]+red[6];
    float SS = red[1]+red[3]+red[5]+red[7];
    float m  = S * inv_cnt;
    float var = SS * inv_cnt - m*m;
    float sc = g[c] * rsqrtf(var + 1e-5f);
    bn[c]    = sc;
    bn[64+c] = beta[c] - m*sc;
  }
}

// ---------------------------------------------------------------------------
// w2 pack: fp32 [co][ci][kh][kw] -> bf16 [khw][co][ci] with the ci-chunk
// XOR-swizzle ((ci>>3)^(co&7)) pre-applied so conv2's LDS copy is linear.
// ---------------------------------------------------------------------------
__global__ __launch_bounds__(256)
void w2_pack(const float* __restrict__ w2, unsigned short* __restrict__ wB)
{
  int i = blockIdx.x*256 + threadIdx.x;   // 9*64*64 = 36864
  if (i < 36864) {
    int khw = i >> 12, rem = i & 4095, co = rem >> 6, ci = rem & 63;
    int chunk = (ci >> 3) ^ (co & 7);
    wB[khw*4096 + co*64 + chunk*8 + (ci & 7)] = f2bf(w2[co*576 + ci*9 + khw]);
  }
}

// ---------------------------------------------------------------------------
// Qw pack: fp32 [100][4196] (first 4096 cols) -> bf16 [112][4096],
// rows 100..111 zeroed (N padded to 7x16 MFMA tiles).
// ---------------------------------------------------------------------------
__global__ __launch_bounds__(256)
void qw_pack(const float* __restrict__ Qw, unsigned short* __restrict__ qB)
{
  int i = blockIdx.x*256 + threadIdx.x;   // 112*4096 = 458752
  if (i < 458752) {
    int j = i >> 12, k = i & 4095;
    qB[i] = (j < 100) ? f2bf(Qw[j*4196 + k]) : (unsigned short)0;
  }
}

// ---------------------------------------------------------------------------
// conv2 via MFMA implicit GEMM. grid 1024 (one image), block 256 (4 waves).
// Staging FUSES conv1's BN affine + ReLU. Pooled raw outputs stored bf16.
// ---------------------------------------------------------------------------
__global__ __launch_bounds__(256)
void conv2_mfma(const unsigned short* __restrict__ pmax1,
                const unsigned short* __restrict__ pmin1,
                const float* __restrict__ bn1,
                const unsigned short* __restrict__ wB,
                float* __restrict__ part,
                unsigned short* __restrict__ pmax2, unsigned short* __restrict__ pmin2)
{
  __shared__ unsigned short xin[324*64];   // 41472 B
  __shared__ unsigned short wL[9*64*64];   // 73728 B
  __shared__ float wred[4][4][16][2];      // 2 KB
  __shared__ float bnL[128];
  const int n = blockIdx.x, tid = threadIdx.x;
  const int w = tid >> 6, lane = tid & 63;
  const int q = lane >> 4, col = lane & 15;

  if (tid < 128) bnL[tid] = bn1[tid];
  // ---- stage weights (linear copy; swizzle pre-applied by w2_pack) ----
  {
    const s8v* src = (const s8v*)wB;
    s8v* dst = (s8v*)wL;
    #pragma unroll
    for (int i = 0; i < 18; ++i) dst[tid + (i<<8)] = src[tid + (i<<8)];
  }
  __syncthreads();   // bnL ready
  // ---- stage input 18x18x64 bf16 = relu(affine(pooled conv1)), halo zeros,
  //      swizzled 16B chunks ----
  {
    #pragma unroll
    for (int k = 0; k < 11; ++k) {
      int i = tid + (k<<8);
      if (i < 324*8) {
        int L = i >> 3, s = i & 7;
        int y = L / 18, x = L - y*18;
        s8v v = (s8v){0,0,0,0,0,0,0,0};
        if (y >= 1 && y <= 16 && x >= 1 && x <= 16) {
          int idx = (((n<<8) + ((y-1)<<4) + (x-1))<<6) + (s<<3);
          s8v mx = *(const s8v*)&pmax1[idx];
          s8v mn = *(const s8v*)&pmin1[idx];
          #pragma unroll
          for (int e = 0; e < 8; ++e) {
            int ci = (s<<3) + e;
            float sc = bnL[ci], sh = bnL[64+ci];
            float vv = bf2f((unsigned short)(sc >= 0.f ? mx[e] : mn[e]));
            v[e] = (short)f2bf(fmaxf(fmaf(vv, sc, sh), 0.f));
          }
        }
        *(s8v*)((char*)xin + L*128 + (((s ^ (L & 7)) << 4))) = v;
      }
    }
  }
  __syncthreads();

  f32x4 acc[4][4];   // [mtile][ntile]
  #pragma unroll
  for (int mt = 0; mt < 4; ++mt)
    #pragma unroll
    for (int t = 0; t < 4; ++t)
      acc[mt][t] = (f32x4){0.f,0.f,0.f,0.f};

  const int py0 = w << 2;   // wave's 4 image rows
  #pragma unroll 1
  for (int khw = 0; khw < 9; ++khw) {
    const int kh = khw / 3, kw = khw - 3*kh;
    const char* wslice = (const char*)wL + khw*8192;
    #pragma unroll
    for (int ks = 0; ks < 2; ++ks) {       // ci0 = 32*ks
      const int chunk = (ks << 2) + q;     // 16B-chunk of k within line
      s8v bfrag[4];
      #pragma unroll
      for (int t = 0; t < 4; ++t) {
        int co = (t << 4) + col;
        bfrag[t] = *(const s8v*)(wslice + co*128 + (((chunk ^ (co & 7)) << 4)));
      }
      #pragma unroll
      for (int mt = 0; mt < 4; ++mt) {
        int L = (py0 + mt + kh)*18 + (col + kw);
        s8v afrag = *(const s8v*)((const char*)xin + L*128 + (((chunk ^ (L & 7)) << 4)));
        #pragma unroll
        for (int t = 0; t < 4; ++t)
          acc[mt][t] = __builtin_amdgcn_mfma_f32_16x16x32_bf16(afrag, bfrag[t], acc[mt][t], 0, 0, 0);
      }
    }
  }

  // ---- stats: per-channel sum / sumsq over this block's 256 pixels ----
  #pragma unroll
  for (int t = 0; t < 4; ++t) {
    float s = 0.f, ss = 0.f;
    #pragma unroll
    for (int mt = 0; mt < 4; ++mt)
      #pragma unroll
      for (int r = 0; r < 4; ++r) {
        float v = acc[mt][t][r];
        s += v; ss = fmaf(v, v, ss);
      }
    s  += __shfl_xor(s, 16);  s  += __shfl_xor(s, 32);
    ss += __shfl_xor(ss, 16); ss += __shfl_xor(ss, 32);
    if (q == 0) { wred[w][t][col][0] = s; wred[w][t][col][1] = ss; }
  }
  __syncthreads();
  if (tid < 64) {
    float s = 0.f, ss = 0.f;
    #pragma unroll
    for (int wv = 0; wv < 4; ++wv) {
      s  += wred[wv][tid >> 4][tid & 15][0];
      ss += wred[wv][tid >> 4][tid & 15][1];
    }
    part[tid*2048 + n*2]     = s;
    part[tid*2048 + n*2 + 1] = ss;
  }

  // ---- 2x2 pooled max AND min of raw conv (affine applied later), bf16 ----
  #pragma unroll
  for (int t = 0; t < 4; ++t) {
    int co = (t << 4) + col;
    #pragma unroll
    for (int mp = 0; mp < 2; ++mp) {          // vertical pair (rows 2mp,2mp+1)
      f32x4 a0 = acc[2*mp][t], a1 = acc[2*mp+1][t];
      float mx0 = fmaxf(fmaxf(a0[0], a0[1]), fmaxf(a1[0], a1[1]));
      float mx1 = fmaxf(fmaxf(a0[2], a0[3]), fmaxf(a1[2], a1[3]));
      float mn0 = fminf(fminf(a0[0], a0[1]), fminf(a1[0], a1[1]));
      float mn1 = fminf(fminf(a0[2], a0[3]), fminf(a1[2], a1[3]));
      int pyp = (w << 1) + mp;                // pooled y
      int base = ((n*64 + co) << 6) + (pyp << 3) + (q << 1);  // feats c*64+p
      pmax2[base] = f2bf(mx0); pmax2[base+1] = f2bf(mx1);
      pmin2[base] = f2bf(mn0); pmin2[base+1] = f2bf(mn1);
    }
  }
}

// ---------------------------------------------------------------------------
// preQ partials via MFMA, fusing conv2's BN affine + ReLU into the A-frag
// load. No LDS. grid (16 mblocks x 16 ksplits), block 256.
// part layout [ks][1024][112] fp32.
// ---------------------------------------------------------------------------
__global__ __launch_bounds__(256)
void preq_mfma(const unsigned short* __restrict__ pmax2,
               const unsigned short* __restrict__ pmin2,
               const float* __restrict__ bn2,
               const unsigned short* __restrict__ qB,
               float* __restrict__ part)
{
  const int mb = blockIdx.x, ks = blockIdx.y, tid = threadIdx.x;
  const int w = tid >> 6, lane = tid & 63;
  const int q = lane >> 4, col = lane & 15;
  const int m = (mb << 6) + (w << 4) + col;    // A row this lane loads
  const int k00 = ks << 8;

  f32x4 acc[7];
  #pragma unroll
  for (int t = 0; t < 7; ++t) acc[t] = (f32x4){0.f,0.f,0.f,0.f};

  #pragma unroll 2
  for (int kk = 0; kk < 8; ++kk) {
    const int k = k00 + (kk << 5) + (q << 3);  // 8-aligned, one c per chunk
    const int c = k >> 6;
    const float sc = bn2[c], sh = bn2[64 + c];
    s8v mx = *(const s8v*)&pmax2[m*4096 + k];
    s8v mn = *(const s8v*)&pmin2[m*4096 + k];
    s8v a;
    #pragma unroll
    for (int e = 0; e < 8; ++e) {
      float vv = bf2f((unsigned short)(sc >= 0.f ? mx[e] : mn[e]));
      a[e] = (short)f2bf(fmaxf(fmaf(vv, sc, sh), 0.f));
    }
    #pragma unroll
    for (int t = 0; t < 7; ++t) {
      s8v b = *(const s8v*)&qB[(((t << 4) + col) << 12) + k];
      acc[t] = __builtin_amdgcn_mfma_f32_16x16x32_bf16(a, b, acc[t], 0, 0, 0);
    }
  }

  // C: col=lane&15 = j16, row=4q+r = m-row within the wave's 16-row tile
  float* dst = part + ks*114688 + ((mb << 6) + (w << 4) + (q << 2))*112;
  #pragma unroll
  for (int t = 0; t < 7; ++t)
    #pragma unroll
    for (int r = 0; r < 4; ++r)
      dst[r*112 + (t << 4) + col] = acc[t][r];
}

// preQ[n][100] = sum_ks part[ks][n][j] + Qb[j].  grid 400, block 256.
__global__ __launch_bounds__(256)
void preq_reduce(const float* __restrict__ part, const float* __restrict__ Qb,
                 float* __restrict__ preQ)
{
  int idx = blockIdx.x*256 + threadIdx.x;  // 102400 exact
  if (idx < 1024*100) {
    int n = idx / 100, j = idx - n*100;
    float s = Qb[j];
    #pragma unroll
    for (int ks = 0; ks < 16; ++ks) s += part[ks*114688 + n*112 + j];
    preQ[idx] = s;
  }
}

// ---------------------------------------------------------------------------
// RNN (64 sequential steps) + head. grid 16 (one block per batch b), block 512.
// R15: Q-phase now fuses the Ha update (2 barriers/step, was 3):
//  - after the quad shfl reduce, ALL 4 threads hold qacc -> each computes qt
//    redundantly (bitwise identical) and thread q4 updates ITS Ha element
//    Ha[q4*100+o], held in a register with write-through to LDS for R-phase.
//  - qt[] LDS array and update-phase LDS reads deleted.
// ---------------------------------------------------------------------------
__global__ __launch_bounds__(512, 2)
void rnn_head(const float* __restrict__ preQ, const float* __restrict__ Rw,
              const float* __restrict__ Rb, const float* __restrict__ Qw,
              const float* __restrict__ Ow, const float* __restrict__ Ob,
              const float* __restrict__ f1w, const float* __restrict__ f1b,
              const float* __restrict__ f2w, const float* __restrict__ f2b,
              float* __restrict__ out)
{
  __shared__ __align__(16) float ha[400];
  __shared__ __align__(16) float rtP[112];   // 4 quarters x 28 (pads zero)
  __shared__ float pq[6400];
  __shared__ float rb[100];
  __shared__ __align__(16) float ol[128];
  __shared__ float f1[64];
  const int b = blockIdx.x, tid = threadIdx.x;

  for (int i = tid; i < 6400; i += 512) pq[i] = preQ[b*6400 + i];
  if (tid < 100) rb[tid] = Rb[tid];
  if (tid < 400) ha[tid] = 0.f;
  if (tid < 112) rtP[tid] = 0.f;             // pads stay zero forever

  const int o = tid >> 2, q4 = tid & 3;
  // rt write slot for thread (o, q4==0): quarter o/25, element o%25
  const int rtSlot = (o / 25)*28 + (o % 25);
  float rw[100], qw[28];
  if (tid < 400) {
    const float* rsrc = &Rw[o*400 + q4*100];
    #pragma unroll
    for (int i = 0; i < 25; ++i) {
      float4 v = *(const float4*)&rsrc[i*4];
      rw[i*4] = v.x; rw[i*4+1] = v.y; rw[i*4+2] = v.z; rw[i*4+3] = v.w;
    }
    const float* qsrc = &Qw[o*4196 + 4096 + q4*25];
    #pragma unroll
    for (int i = 0; i < 25; ++i) qw[i] = qsrc[i];
    qw[25] = 0.f; qw[26] = 0.f; qw[27] = 0.f;   // multiply rtP pads
  }
  // this thread's Ha element: Ha[q4*100 + o], decay A[q4]; kept in haReg
  const float Aa = (q4==0) ? 0.f : (q4==1) ? 0.25f : (q4==2) ? 0.5f : 0.95f;
  const float Ba = 1.f - Aa;
  float haReg = 0.f;
  __syncthreads();

  for (int t = 0; t < 64; ++t) {
    if (tid < 400) {
      // R: 4 independent fmaf chains over the 100-wide quarter
      float r0 = 0.f, r1 = 0.f, r2 = 0.f, r3 = 0.f;
      const float* hp = &ha[q4*100];
      #pragma unroll
      for (int i = 0; i < 25; i += 4) {
        float4 a0 = *(const float4*)&hp[i*4];
        float4 a1 = *(const float4*)&hp[i*4+4];
        float4 a2 = *(const float4*)&hp[i*4+8];
        float4 a3 = *(const float4*)&hp[i*4+12];
        r0 = fmaf(rw[i*4],    a0.x, r0); r0 = fmaf(rw[i*4+1],  a0.y, r0);
        r0 = fmaf(rw[i*4+2],  a0.z, r0); r0 = fmaf(rw[i*4+3],  a0.w, r0);
        if (i+1 < 25) {
          r1 = fmaf(rw[i*4+4],  a1.x, r1); r1 = fmaf(rw[i*4+5],  a1.y, r1);
          r1 = fmaf(rw[i*4+6],  a1.z, r1); r1 = fmaf(rw[i*4+7],  a1.w, r1);
        }
        if (i+2 < 25) {
          r2 = fmaf(rw[i*4+8],  a2.x, r2); r2 = fmaf(rw[i*4+9],  a2.y, r2);
          r2 = fmaf(rw[i*4+10], a2.z, r2); r2 = fmaf(rw[i*4+11], a2.w, r2);
        }
        if (i+3 < 25) {
          r3 = fmaf(rw[i*4+12], a3.x, r3); r3 = fmaf(rw[i*4+13], a3.y, r3);
          r3 = fmaf(rw[i*4+14], a3.z, r3); r3 = fmaf(rw[i*4+15], a3.w, r3);
        }
      }
      float racc = (r0 + r1) + (r2 + r3);
      racc += __shfl_xor(racc, 1);
      racc += __shfl_xor(racc, 2);
      if (q4 == 0) rtP[rtSlot] = ftanh(racc + rb[o]);
    }
    __syncthreads();
    if (tid < 400) {
      // Q: 7 float4 reads of the padded quarter, 2 chains; FUSED Ha update
      float s0 = 0.f, s1 = 0.f;
      const float* rp = &rtP[q4*28];
      #pragma unroll
      for (int i = 0; i < 7; i += 2) {
        float4 v0 = *(const float4*)&rp[i*4];
        s0 = fmaf(qw[i*4],   v0.x, s0); s0 = fmaf(qw[i*4+1], v0.y, s0);
        s0 = fmaf(qw[i*4+2], v0.z, s0); s0 = fmaf(qw[i*4+3], v0.w, s0);
        if (i+1 < 7) {
          float4 v1 = *(const float4*)&rp[i*4+4];
          s1 = fmaf(qw[i*4+4], v1.x, s1); s1 = fmaf(qw[i*4+5], v1.y, s1);
          s1 = fmaf(qw[i*4+6], v1.z, s1); s1 = fmaf(qw[i*4+7], v1.w, s1);
        }
      }
      float qacc = s0 + s1;
      qacc += __shfl_xor(qacc, 1);
      qacc += __shfl_xor(qacc, 2);
      // all 4 quad threads now hold identical qacc
      float qt = ftanh(qacc + pq[t*100 + o]);
      haReg = fmaf(Aa, haReg, Ba*qt);
      ha[q4*100 + o] = haReg;           // write-through for next R-phase
    }
    __syncthreads();
  }

  // head: out_last = tanh(Hf @ Ow^T + Ob), 2 threads per output
  if (tid < 256) {
    const int j2 = tid >> 1, hh = tid & 1;
    const float* osrc = &Ow[j2*400 + hh*200];
    const float* hp = &ha[hh*200];
    float oacc = 0.f;
    #pragma unroll
    for (int i = 0; i < 50; ++i) {
      float4 w4 = *(const float4*)&osrc[i*4];
      float4 h4 = *(const float4*)&hp[i*4];
      oacc = fmaf(w4.x, h4.x, oacc); oacc = fmaf(w4.y, h4.y, oacc);
      oacc = fmaf(w4.z, h4.z, oacc); oacc = fmaf(w4.w, h4.w, oacc);
    }
    oacc += __shfl_xor(oacc, 1);
    if (hh == 0) ol[j2] = ftanh(oacc + Ob[j2]);
  }
  __syncthreads();
  if (tid < 64) {
    float a = 0.f;
    #pragma unroll
    for (int i = 0; i < 32; ++i) {
      float4 w4 = *(const float4*)&f1w[tid*128 + i*4];
      float4 o4 = *(const float4*)&ol[i*4];
      a = fmaf(w4.x, o4.x, a); a = fmaf(w4.y, o4.y, a);
      a = fmaf(w4.z, o4.z, a); a = fmaf(w4.w, o4.w, a);
    }
    f1[tid] = fmaxf(a + f1b[tid], 0.f);
  }
  __syncthreads();
  if (tid == 0) {
    float a = 0.f;
    for (int i = 0; i < 64; ++i) a = fmaf(f2w[i], f1[i], a);
    out[b] = __builtin_amdgcn_rcpf(1.f + __expf(-a));
  }
}

// ---------------------------------------------------------------------------
extern "C" void kernel_launch(void* const* d_in, const int* in_sizes, int n_in,
                              void* d_out, int out_size, void* d_ws, size_t ws_size,
                              hipStream_t stream) {
  (void)in_sizes; (void)n_in; (void)out_size; (void)ws_size;
  const float* x1   = (const float*)d_in[0];
  const float* x2   = (const float*)d_in[1];
  const float* c1w  = (const float*)d_in[2];
  // d_in[3] conv1_b: cancels in BN
  const float* bn1g = (const float*)d_in[4];
  const float* bn1b = (const float*)d_in[5];
  const float* c2w  = (const float*)d_in[6];
  // d_in[7] conv2_b: cancels in BN
  const float* bn2g = (const float*)d_in[8];
  const float* bn2b = (const float*)d_in[9];
  const float* Rw   = (const float*)d_in[10];
  const float* Rb   = (const float*)d_in[11];
  const float* Qw   = (const float*)d_in[12];
  const float* Qb   = (const float*)d_in[13];
  const float* Ow   = (const float*)d_in[14];
  const float* Ob   = (const float*)d_in[15];
  const float* f1w  = (const float*)d_in[16];
  const float* f1b  = (const float*)d_in[17];
  const float* f2w  = (const float*)d_in[18];
  const float* f2b  = (const float*)d_in[19];
  float* outp = (float*)d_out;

  // workspace layout (bytes); total ~90 MB
  char* wsb = (char*)d_ws;
  unsigned short* pmax1 = (unsigned short*)wsb;                 // 33,554,432 B
  unsigned short* pmin1 = (unsigned short*)(wsb + 33554432);    // 33,554,432 B
  unsigned short* pmax2 = (unsigned short*)(wsb + 67108864);    //  8,388,608 B
  unsigned short* pmin2 = (unsigned short*)(wsb + 75497472);    //  8,388,608 B
  float* part1  = (float*)(wsb + 83886080);                     // 524,288 B
  float* part2  = part1 + 131072;                               // 524,288 B
  float* bn1    = part2 + 131072;                               // 512 B
  float* bn2    = bn1 + 128;                                    // 512 B
  float* preQ   = bn2 + 128;                                    // 409,600 B
  unsigned short* wB1 = (unsigned short*)(preQ + 102400);       // 12,288 B
  unsigned short* wB2 = wB1 + 6144;                             // 73,728 B
  unsigned short* qB  = wB2 + 36864;                            // 917,504 B
  float* pqpart = (float*)(qB + 458752);                        // 7,340,032 B

  w1_pack<<<24, 256, 0, stream>>>(c1w, wB1);
  w2_pack<<<144, 256, 0, stream>>>(c2w, wB2);
  qw_pack<<<1792, 256, 0, stream>>>(Qw, qB);
  conv1_mfma<<<1024, 256, 0, stream>>>(x1, x2, wB1, part1, pmax1, pmin1);
  bn_finalize<<<64, 256, 0, stream>>>(part1, bn1g, bn1b, 1.f/1048576.f, bn1);
  conv2_mfma<<<1024, 256, 0, stream>>>(pmax1, pmin1, bn1, wB2, part2, pmax2, pmin2);
  bn_finalize<<<64, 256, 0, stream>>>(part2, bn2g, bn2b, 1.f/262144.f, bn2);
  preq_mfma<<<dim3(16,16), 256, 0, stream>>>(pmax2, pmin2, bn2, qB, pqpart);
  preq_reduce<<<400, 256, 0, stream>>>(pqpart, Qb, preQ);
  rnn_head<<<16, 512, 0, stream>>>(preQ, Rw, Rb, Qw, Ow, Ob, f1w, f1b, f2w, f2b, outp);
}

// Round 16
// 172.388 us; speedup vs baseline: 1.8034x; 1.0824x over previous
//
#include <hip/hip_runtime.h>
#include <math.h>

// Problem constants
// x: (16,64,3,32,32) x2 concat -> (1024,6,32,32)
// conv1 6->64 k3 p1 -> BN -> ReLU -> pool2 -> (1024,64,16,16)
// conv2 64->64 k3 p1 -> BN -> ReLU -> pool2 -> (1024,64,8,8) = feats (1024,4096)
// RNN T=64 steps over feats rows n=b*64+t ; head -> sigmoid (16,1)
//
// R16: sign(bn scale) = sign(gamma) (input!) -> pooled max/min selection done
// at the PRODUCER; single pooled array per conv (conv1 writes 67->33MB,
// conv2 reads 67->33MB writes 16.7->8.4MB, preq reads halve). Packs merged.
// RNN = R15 version (94->85->82->77us ladder; latency floor ~75us).

typedef __attribute__((ext_vector_type(8))) short s8v;   // 8 bf16 (4 VGPRs)
typedef __attribute__((ext_vector_type(4))) float f32x4;

__device__ __forceinline__ unsigned short f2bf(float f) {
  union { float f; unsigned u; } x; x.f = f;
  return (unsigned short)((x.u + 0x7FFFu + ((x.u >> 16) & 1u)) >> 16);  // RNE
}
__device__ __forceinline__ float bf2f(unsigned short u) {
  union { unsigned u; float f; } x; x.u = ((unsigned)u) << 16; return x.f;
}
// fast tanh: 1 - 2/(e^{2x}+1); inf-safe via rcp (e=inf -> 0 -> +1; e->0 -> -1)
__device__ __forceinline__ float ftanh(float x) {
  float e = __expf(2.f * x);
  return 1.f - 2.f * __builtin_amdgcn_rcpf(e + 1.f);
}

// ---------------------------------------------------------------------------
// pack_all: w1 -> bf16 [kh][64co][32k] (k=kw*6+ci, zero pad k>=18);
//           w2 -> bf16 [khw][co][ci] with ci-chunk XOR swizzle;
//           Qw[:, :4096] -> bf16 [112][4096] (rows >=100 zero).
// ---------------------------------------------------------------------------
__global__ __launch_bounds__(256)
void pack_all(const float* __restrict__ w1, const float* __restrict__ w2,
              const float* __restrict__ Qw,
              unsigned short* __restrict__ wB1, unsigned short* __restrict__ wB2,
              unsigned short* __restrict__ qB)
{
  int i = blockIdx.x*256 + threadIdx.x;   // 6144 + 36864 + 458752 = 501760
  if (i < 6144) {
    int kh = i >> 11, rem = i & 2047, co = rem >> 5, k2 = rem & 31;
    unsigned short v = 0;
    if (k2 < 18) {
      int kw = k2 / 6, ci = k2 - 6*kw;
      v = f2bf(w1[co*54 + ci*9 + kh*3 + kw]);
    }
    wB1[i] = v;
  } else if (i < 43008) {
    int j = i - 6144;
    int khw = j >> 12, rem = j & 4095, co = rem >> 6, ci = rem & 63;
    int chunk = (ci >> 3) ^ (co & 7);
    wB2[khw*4096 + co*64 + chunk*8 + (ci & 7)] = f2bf(w2[co*576 + ci*9 + khw]);
  } else if (i < 501760) {
    int j = i - 43008;
    int row = j >> 12, k = j & 4095;
    qB[j] = (row < 100) ? f2bf(Qw[row*4196 + k]) : (unsigned short)0;
  }
}

// ---------------------------------------------------------------------------
// conv1 via MFMA implicit GEMM, computed ONCE. grid 1024, block 256 (4 waves).
// R16: epilogue stores ONE pooled value per (pixel, channel): max if
// gamma1[c] >= 0 else min (sign(bn scale) == sign(gamma)). 33 MB not 67.
// ---------------------------------------------------------------------------
__global__ __launch_bounds__(256, 4)
void conv1_mfma(const float* __restrict__ x1, const float* __restrict__ x2,
                const unsigned short* __restrict__ wB1,
                const float* __restrict__ bn1g,
                float* __restrict__ part, unsigned short* __restrict__ pool1s)
{
  __shared__ unsigned xin[3688];          // 34 rows x 108 dwords + 16 pad
  __shared__ float wred[4][4][16][2];
  __shared__ float gsel[64];
  const int n = blockIdx.x, tid = threadIdx.x;
  const int w = tid >> 6, lane = tid & 63;
  const int q = lane >> 4, r = lane & 15;

  if (tid < 64) gsel[tid] = bn1g[tid];

  // B fragments, whole kernel in regs: bf[kh][t], co = 16t + r, k0 = 8q
  s8v bf[3][4];
  #pragma unroll
  for (int kh = 0; kh < 3; ++kh)
    #pragma unroll
    for (int t = 0; t < 4; ++t)
      bf[kh][t] = *(const s8v*)&wB1[kh*2048 + (((t<<4)+r)<<5) + (q<<3)];

  // zero ALL of xin (incl. pad tail) -- overread garbage must be finite
  #pragma unroll
  for (int k = 0; k < 15; ++k) {
    int i = tid + (k<<8);
    if (i < 3688) xin[i] = 0;
  }
  __syncthreads();
  // interior fill: dword (y+1)*108 + (x+1)*3 + cp packs bf16{ci=2cp,2cp+1}
  #pragma unroll
  for (int k = 0; k < 12; ++k) {
    int i = tid + (k<<8);     // 0..3071
    int cp = i >> 10, p = i & 1023;
    int y = p >> 5, x = p & 31;
    float lo, hi;
    if (cp == 0)      { lo = x1[n*3072 + p];        hi = x1[n*3072 + 1024 + p]; }
    else if (cp == 1) { lo = x1[n*3072 + 2048 + p]; hi = x2[n*3072 + p];        }
    else              { lo = x2[n*3072 + 1024 + p]; hi = x2[n*3072 + 2048 + p]; }
    xin[(y+1)*108 + (x+1)*3 + cp] = (unsigned)f2bf(lo) | ((unsigned)f2bf(hi) << 16);
  }
  __syncthreads();

  float st[4], sq[4];
  #pragma unroll
  for (int t = 0; t < 4; ++t) { st[t] = 0.f; sq[t] = 0.f; }
  float pmx[4][2], pmn[4][2];

  #pragma unroll 1
  for (int xb = 0; xb < 2; ++xb) {
    const int xbase = xb << 4;
    #pragma unroll 2
    for (int j = 0; j < 8; ++j) {           // y = 8w + j
      const int y = (w << 3) + j;
      f32x4 acc[4];
      #pragma unroll
      for (int t = 0; t < 4; ++t) acc[t] = (f32x4){0.f,0.f,0.f,0.f};
      #pragma unroll
      for (int kh = 0; kh < 3; ++kh) {      // k-step == kh slice
        int dw = (y + kh)*108 + 3*(xbase + r) + (q << 2);
        union { unsigned u[4]; s8v v; } af;
        af.u[0] = xin[dw];   af.u[1] = xin[dw+1];
        af.u[2] = xin[dw+2]; af.u[3] = xin[dw+3];
        #pragma unroll
        for (int t = 0; t < 4; ++t)
          acc[t] = __builtin_amdgcn_mfma_f32_16x16x32_bf16(af.v, bf[kh][t], acc[t], 0, 0, 0);
      }
      #pragma unroll
      for (int t = 0; t < 4; ++t) {
        st[t] += acc[t][0]+acc[t][1]+acc[t][2]+acc[t][3];
        sq[t] = fmaf(acc[t][0],acc[t][0], fmaf(acc[t][1],acc[t][1],
                fmaf(acc[t][2],acc[t][2], fmaf(acc[t][3],acc[t][3], sq[t]))));
      }
      if ((j & 1) == 0) {                   // even y: stash x-pair max/min
        #pragma unroll
        for (int t = 0; t < 4; ++t) {
          pmx[t][0] = fmaxf(acc[t][0], acc[t][1]); pmx[t][1] = fmaxf(acc[t][2], acc[t][3]);
          pmn[t][0] = fminf(acc[t][0], acc[t][1]); pmn[t][1] = fminf(acc[t][2], acc[t][3]);
        }
      } else {                              // odd y: combine + write pooled sel
        const int py = y >> 1;
        #pragma unroll
        for (int t = 0; t < 4; ++t) {
          int co = (t << 4) + r;
          const bool useMax = (gsel[co] >= 0.f);
          #pragma unroll
          for (int pp = 0; pp < 2; ++pp) {
            float mx = fmaxf(pmx[t][pp], fmaxf(acc[t][2*pp], acc[t][2*pp+1]));
            float mn = fminf(pmn[t][pp], fminf(acc[t][2*pp], acc[t][2*pp+1]));
            int pxp = (xb << 3) + (q << 1) + pp;
            int o = (((n << 8) + (py << 4) + pxp) << 6) + co;
            pool1s[o] = f2bf(useMax ? mx : mn);
          }
        }
      }
    }
  }

  #pragma unroll
  for (int t = 0; t < 4; ++t) {
    float s = st[t], ss = sq[t];
    s  += __shfl_xor(s, 16);  s  += __shfl_xor(s, 32);
    ss += __shfl_xor(ss, 16); ss += __shfl_xor(ss, 32);
    if (q == 0) { wred[w][t][r][0] = s; wred[w][t][r][1] = ss; }
  }
  __syncthreads();
  if (tid < 64) {
    float s = 0.f, ss = 0.f;
    #pragma unroll
    for (int wv = 0; wv < 4; ++wv) {
      s  += wred[wv][tid >> 4][tid & 15][0];
      ss += wred[wv][tid >> 4][tid & 15][1];
    }
    part[tid*2048 + n*2]     = s;     // layout [c][n][2]
    part[tid*2048 + n*2 + 1] = ss;
  }
}

// ---------------------------------------------------------------------------
// BN finalize: per-channel mean/var -> scale/shift.  grid 64, block 256.
// ---------------------------------------------------------------------------
__global__ __launch_bounds__(256)
void bn_finalize(const float* __restrict__ part, const float* __restrict__ g,
                 const float* __restrict__ beta, float inv_cnt, float* __restrict__ bn)
{
  __shared__ float red[8];
  const int c = blockIdx.x, tid = threadIdx.x;
  float s = 0.f, ss = 0.f;
  for (int n = tid; n < 1024; n += 256) {
    s  += part[c*2048 + n*2];
    ss += part[c*2048 + n*2 + 1];
  }
  #pragma unroll
  for (int d = 32; d; d >>= 1) { s += __shfl_xor(s, d); ss += __shfl_xor(ss, d); }
  if ((tid & 63) == 0) { red[(tid>>6)*2] = s; red[(tid>>6)*2+1] = ss; }
  __syncthreads();
  if (tid == 0) {
    float S  = red[0]+red[2]+red[4]+red[6];
    float SS = red[1]+red[3]+red[5]+red[7];
    float m  = S * inv_cnt;
    float var = SS * inv_cnt - m*m;
    float sc = g[c] * rsqrtf(var + 1e-5f);
    bn[c]    = sc;
    bn[64+c] = beta[c] - m*sc;
  }
}

// ---------------------------------------------------------------------------
// conv2 via MFMA implicit GEMM. grid 1024 (one image), block 256 (4 waves).
// Staging fuses conv1 BN affine + ReLU reading the single pool1s array.
// Epilogue stores single pooled sel per channel via sign(gamma2). 8.4 MB.
// ---------------------------------------------------------------------------
__global__ __launch_bounds__(256)
void conv2_mfma(const unsigned short* __restrict__ pool1s,
                const float* __restrict__ bn1,
                const float* __restrict__ bn2g,
                const unsigned short* __restrict__ wB,
                float* __restrict__ part, unsigned short* __restrict__ psel2)
{
  __shared__ unsigned short xin[324*64];   // 41472 B
  __shared__ unsigned short wL[9*64*64];   // 73728 B
  __shared__ float wred[4][4][16][2];      // 2 KB
  __shared__ float bnL[128];
  __shared__ float g2L[64];
  const int n = blockIdx.x, tid = threadIdx.x;
  const int w = tid >> 6, lane = tid & 63;
  const int q = lane >> 4, col = lane & 15;

  if (tid < 128) bnL[tid] = bn1[tid];
  if (tid >= 128 && tid < 192) g2L[tid - 128] = bn2g[tid - 128];
  // ---- stage weights (linear copy; swizzle pre-applied in pack) ----
  {
    const s8v* src = (const s8v*)wB;
    s8v* dst = (s8v*)wL;
    #pragma unroll
    for (int i = 0; i < 18; ++i) dst[tid + (i<<8)] = src[tid + (i<<8)];
  }
  __syncthreads();   // bnL/g2L ready
  // ---- stage input 18x18x64 bf16 = relu(affine(pool1s)), halo zeros,
  //      swizzled 16B chunks ----
  {
    #pragma unroll
    for (int k = 0; k < 11; ++k) {
      int i = tid + (k<<8);
      if (i < 324*8) {
        int L = i >> 3, s = i & 7;
        int y = L / 18, x = L - y*18;
        s8v v = (s8v){0,0,0,0,0,0,0,0};
        if (y >= 1 && y <= 16 && x >= 1 && x <= 16) {
          int idx = (((n<<8) + ((y-1)<<4) + (x-1))<<6) + (s<<3);
          s8v sv = *(const s8v*)&pool1s[idx];
          #pragma unroll
          for (int e = 0; e < 8; ++e) {
            int ci = (s<<3) + e;
            float sc = bnL[ci], sh = bnL[64+ci];
            float vv = bf2f((unsigned short)sv[e]);
            v[e] = (short)f2bf(fmaxf(fmaf(vv, sc, sh), 0.f));
          }
        }
        *(s8v*)((char*)xin + L*128 + (((s ^ (L & 7)) << 4))) = v;
      }
    }
  }
  __syncthreads();

  f32x4 acc[4][4];   // [mtile][ntile]
  #pragma unroll
  for (int mt = 0; mt < 4; ++mt)
    #pragma unroll
    for (int t = 0; t < 4; ++t)
      acc[mt][t] = (f32x4){0.f,0.f,0.f,0.f};

  const int py0 = w << 2;   // wave's 4 image rows
  #pragma unroll 1
  for (int khw = 0; khw < 9; ++khw) {
    const int kh = khw / 3, kw = khw - 3*kh;
    const char* wslice = (const char*)wL + khw*8192;
    #pragma unroll
    for (int ks = 0; ks < 2; ++ks) {       // ci0 = 32*ks
      const int chunk = (ks << 2) + q;     // 16B-chunk of k within line
      s8v bfrag[4];
      #pragma unroll
      for (int t = 0; t < 4; ++t) {
        int co = (t << 4) + col;
        bfrag[t] = *(const s8v*)(wslice + co*128 + (((chunk ^ (co & 7)) << 4)));
      }
      #pragma unroll
      for (int mt = 0; mt < 4; ++mt) {
        int L = (py0 + mt + kh)*18 + (col + kw);
        s8v afrag = *(const s8v*)((const char*)xin + L*128 + (((chunk ^ (L & 7)) << 4)));
        #pragma unroll
        for (int t = 0; t < 4; ++t)
          acc[mt][t] = __builtin_amdgcn_mfma_f32_16x16x32_bf16(afrag, bfrag[t], acc[mt][t], 0, 0, 0);
      }
    }
  }

  // ---- stats: per-channel sum / sumsq over this block's 256 pixels ----
  #pragma unroll
  for (int t = 0; t < 4; ++t) {
    float s = 0.f, ss = 0.f;
    #pragma unroll
    for (int mt = 0; mt < 4; ++mt)
      #pragma unroll
      for (int r = 0; r < 4; ++r) {
        float v = acc[mt][t][r];
        s += v; ss = fmaf(v, v, ss);
      }
    s  += __shfl_xor(s, 16);  s  += __shfl_xor(s, 32);
    ss += __shfl_xor(ss, 16); ss += __shfl_xor(ss, 32);
    if (q == 0) { wred[w][t][col][0] = s; wred[w][t][col][1] = ss; }
  }
  __syncthreads();
  if (tid < 64) {
    float s = 0.f, ss = 0.f;
    #pragma unroll
    for (int wv = 0; wv < 4; ++wv) {
      s  += wred[wv][tid >> 4][tid & 15][0];
      ss += wred[wv][tid >> 4][tid & 15][1];
    }
    part[tid*2048 + n*2]     = s;
    part[tid*2048 + n*2 + 1] = ss;
  }

  // ---- 2x2 pooled sel (max if gamma2>=0 else min) of raw conv, bf16 ----
  #pragma unroll
  for (int t = 0; t < 4; ++t) {
    int co = (t << 4) + col;
    const bool useMax = (g2L[co] >= 0.f);
    #pragma unroll
    for (int mp = 0; mp < 2; ++mp) {          // vertical pair (rows 2mp,2mp+1)
      f32x4 a0 = acc[2*mp][t], a1 = acc[2*mp+1][t];
      float v0, v1;
      if (useMax) {
        v0 = fmaxf(fmaxf(a0[0], a0[1]), fmaxf(a1[0], a1[1]));
        v1 = fmaxf(fmaxf(a0[2], a0[3]), fmaxf(a1[2], a1[3]));
      } else {
        v0 = fminf(fminf(a0[0], a0[1]), fminf(a1[0], a1[1]));
        v1 = fminf(fminf(a0[2], a0[3]), fminf(a1[2], a1[3]));
      }
      int pyp = (w << 1) + mp;                // pooled y
      int base = ((n*64 + co) << 6) + (pyp << 3) + (q << 1);  // feats c*64+p
      psel2[base] = f2bf(v0); psel2[base+1] = f2bf(v1);
    }
  }
}

// ---------------------------------------------------------------------------
// preQ partials via MFMA, fusing conv2's BN affine + ReLU into the A-frag
// load (single psel2 array). No LDS. grid (16 mblocks x 16 ksplits).
// part layout [ks][1024][112] fp32.
// ---------------------------------------------------------------------------
__global__ __launch_bounds__(256)
void preq_mfma(const unsigned short* __restrict__ psel2,
               const float* __restrict__ bn2,
               const unsigned short* __restrict__ qB,
               float* __restrict__ part)
{
  const int mb = blockIdx.x, ks = blockIdx.y, tid = threadIdx.x;
  const int w = tid >> 6, lane = tid & 63;
  const int q = lane >> 4, col = lane & 15;
  const int m = (mb << 6) + (w << 4) + col;    // A row this lane loads
  const int k00 = ks << 8;

  f32x4 acc[7];
  #pragma unroll
  for (int t = 0; t < 7; ++t) acc[t] = (f32x4){0.f,0.f,0.f,0.f};

  #pragma unroll 2
  for (int kk = 0; kk < 8; ++kk) {
    const int k = k00 + (kk << 5) + (q << 3);  // 8-aligned, one c per chunk
    const int c = k >> 6;
    const float sc = bn2[c], sh = bn2[64 + c];
    s8v sv = *(const s8v*)&psel2[m*4096 + k];
    s8v a;
    #pragma unroll
    for (int e = 0; e < 8; ++e)
      a[e] = (short)f2bf(fmaxf(fmaf(bf2f((unsigned short)sv[e]), sc, sh), 0.f));
    #pragma unroll
    for (int t = 0; t < 7; ++t) {
      s8v bb = *(const s8v*)&qB[(((t << 4) + col) << 12) + k];
      acc[t] = __builtin_amdgcn_mfma_f32_16x16x32_bf16(a, bb, acc[t], 0, 0, 0);
    }
  }

  // C: col=lane&15 = j16, row=4q+r = m-row within the wave's 16-row tile
  float* dst = part + ks*114688 + ((mb << 6) + (w << 4) + (q << 2))*112;
  #pragma unroll
  for (int t = 0; t < 7; ++t)
    #pragma unroll
    for (int r = 0; r < 4; ++r)
      dst[r*112 + (t << 4) + col] = acc[t][r];
}

// preQ[n][100] = sum_ks part[ks][n][j] + Qb[j].  grid 400, block 256.
__global__ __launch_bounds__(256)
void preq_reduce(const float* __restrict__ part, const float* __restrict__ Qb,
                 float* __restrict__ preQ)
{
  int idx = blockIdx.x*256 + threadIdx.x;  // 102400 exact
  if (idx < 1024*100) {
    int n = idx / 100, j = idx - n*100;
    float s = Qb[j];
    #pragma unroll
    for (int ks = 0; ks < 16; ++ks) s += part[ks*114688 + n*112 + j];
    preQ[idx] = s;
  }
}

// ---------------------------------------------------------------------------
// RNN (64 sequential steps) + head. grid 16 (one block per batch b), block 512.
// R15 structure: Q-phase fuses Ha update (2 barriers/step); Ha element in a
// register with write-through; rt padded 4x28 for b128 reads; ftanh.
// ---------------------------------------------------------------------------
__global__ __launch_bounds__(512, 2)
void rnn_head(const float* __restrict__ preQ, const float* __restrict__ Rw,
              const float* __restrict__ Rb, const float* __restrict__ Qw,
              const float* __restrict__ Ow, const float* __restrict__ Ob,
              const float* __restrict__ f1w, const float* __restrict__ f1b,
              const float* __restrict__ f2w, const float* __restrict__ f2b,
              float* __restrict__ out)
{
  __shared__ __align__(16) float ha[400];
  __shared__ __align__(16) float rtP[112];   // 4 quarters x 28 (pads zero)
  __shared__ float pq[6400];
  __shared__ float rb[100];
  __shared__ __align__(16) float ol[128];
  __shared__ float f1[64];
  const int b = blockIdx.x, tid = threadIdx.x;

  for (int i = tid; i < 6400; i += 512) pq[i] = preQ[b*6400 + i];
  if (tid < 100) rb[tid] = Rb[tid];
  if (tid < 400) ha[tid] = 0.f;
  if (tid < 112) rtP[tid] = 0.f;             // pads stay zero forever

  const int o = tid >> 2, q4 = tid & 3;
  const int rtSlot = (o / 25)*28 + (o % 25);
  float rw[100], qw[28];
  if (tid < 400) {
    const float* rsrc = &Rw[o*400 + q4*100];
    #pragma unroll
    for (int i = 0; i < 25; ++i) {
      float4 v = *(const float4*)&rsrc[i*4];
      rw[i*4] = v.x; rw[i*4+1] = v.y; rw[i*4+2] = v.z; rw[i*4+3] = v.w;
    }
    const float* qsrc = &Qw[o*4196 + 4096 + q4*25];
    #pragma unroll
    for (int i = 0; i < 25; ++i) qw[i] = qsrc[i];
    qw[25] = 0.f; qw[26] = 0.f; qw[27] = 0.f;   // multiply rtP pads
  }
  const float Aa = (q4==0) ? 0.f : (q4==1) ? 0.25f : (q4==2) ? 0.5f : 0.95f;
  const float Ba = 1.f - Aa;
  float haReg = 0.f;
  __syncthreads();

  for (int t = 0; t < 64; ++t) {
    if (tid < 400) {
      float r0 = 0.f, r1 = 0.f, r2 = 0.f, r3 = 0.f;
      const float* hp = &ha[q4*100];
      #pragma unroll
      for (int i = 0; i < 25; i += 4) {
        float4 a0 = *(const float4*)&hp[i*4];
        float4 a1 = *(const float4*)&hp[i*4+4];
        float4 a2 = *(const float4*)&hp[i*4+8];
        float4 a3 = *(const float4*)&hp[i*4+12];
        r0 = fmaf(rw[i*4],    a0.x, r0); r0 = fmaf(rw[i*4+1],  a0.y, r0);
        r0 = fmaf(rw[i*4+2],  a0.z, r0); r0 = fmaf(rw[i*4+3],  a0.w, r0);
        if (i+1 < 25) {
          r1 = fmaf(rw[i*4+4],  a1.x, r1); r1 = fmaf(rw[i*4+5],  a1.y, r1);
          r1 = fmaf(rw[i*4+6],  a1.z, r1); r1 = fmaf(rw[i*4+7],  a1.w, r1);
        }
        if (i+2 < 25) {
          r2 = fmaf(rw[i*4+8],  a2.x, r2); r2 = fmaf(rw[i*4+9],  a2.y, r2);
          r2 = fmaf(rw[i*4+10], a2.z, r2); r2 = fmaf(rw[i*4+11], a2.w, r2);
        }
        if (i+3 < 25) {
          r3 = fmaf(rw[i*4+12], a3.x, r3); r3 = fmaf(rw[i*4+13], a3.y, r3);
          r3 = fmaf(rw[i*4+14], a3.z, r3); r3 = fmaf(rw[i*4+15], a3.w, r3);
        }
      }
      float racc = (r0 + r1) + (r2 + r3);
      racc += __shfl_xor(racc, 1);
      racc += __shfl_xor(racc, 2);
      if (q4 == 0) rtP[rtSlot] = ftanh(racc + rb[o]);
    }
    __syncthreads();
    if (tid < 400) {
      float s0 = 0.f, s1 = 0.f;
      const float* rp = &rtP[q4*28];
      #pragma unroll
      for (int i = 0; i < 7; i += 2) {
        float4 v0 = *(const float4*)&rp[i*4];
        s0 = fmaf(qw[i*4],   v0.x, s0); s0 = fmaf(qw[i*4+1], v0.y, s0);
        s0 = fmaf(qw[i*4+2], v0.z, s0); s0 = fmaf(qw[i*4+3], v0.w, s0);
        if (i+1 < 7) {
          float4 v1 = *(const float4*)&rp[i*4+4];
          s1 = fmaf(qw[i*4+4], v1.x, s1); s1 = fmaf(qw[i*4+5], v1.y, s1);
          s1 = fmaf(qw[i*4+6], v1.z, s1); s1 = fmaf(qw[i*4+7], v1.w, s1);
        }
      }
      float qacc = s0 + s1;
      qacc += __shfl_xor(qacc, 1);
      qacc += __shfl_xor(qacc, 2);
      float qt = ftanh(qacc + pq[t*100 + o]);
      haReg = fmaf(Aa, haReg, Ba*qt);
      ha[q4*100 + o] = haReg;           // write-through for next R-phase
    }
    __syncthreads();
  }

  // head: out_last = tanh(Hf @ Ow^T + Ob), 2 threads per output
  if (tid < 256) {
    const int j2 = tid >> 1, hh = tid & 1;
    const float* osrc = &Ow[j2*400 + hh*200];
    const float* hp = &ha[hh*200];
    float oacc = 0.f;
    #pragma unroll
    for (int i = 0; i < 50; ++i) {
      float4 w4 = *(const float4*)&osrc[i*4];
      float4 h4 = *(const float4*)&hp[i*4];
      oacc = fmaf(w4.x, h4.x, oacc); oacc = fmaf(w4.y, h4.y, oacc);
      oacc = fmaf(w4.z, h4.z, oacc); oacc = fmaf(w4.w, h4.w, oacc);
    }
    oacc += __shfl_xor(oacc, 1);
    if (hh == 0) ol[j2] = ftanh(oacc + Ob[j2]);
  }
  __syncthreads();
  if (tid < 64) {
    float a = 0.f;
    #pragma unroll
    for (int i = 0; i < 32; ++i) {
      float4 w4 = *(const float4*)&f1w[tid*128 + i*4];
      float4 o4 = *(const float4*)&ol[i*4];
      a = fmaf(w4.x, o4.x, a); a = fmaf(w4.y, o4.y, a);
      a = fmaf(w4.z, o4.z, a); a = fmaf(w4.w, o4.w, a);
    }
    f1[tid] = fmaxf(a + f1b[tid], 0.f);
  }
  __syncthreads();
  if (tid == 0) {
    float a = 0.f;
    for (int i = 0; i < 64; ++i) a = fmaf(f2w[i], f1[i], a);
    out[b] = __builtin_amdgcn_rcpf(1.f + __expf(-a));
  }
}

// ---------------------------------------------------------------------------
extern "C" void kernel_launch(void* const* d_in, const int* in_sizes, int n_in,
                              void* d_out, int out_size, void* d_ws, size_t ws_size,
                              hipStream_t stream) {
  (void)in_sizes; (void)n_in; (void)out_size; (void)ws_size;
  const float* x1   = (const float*)d_in[0];
  const float* x2   = (const float*)d_in[1];
  const float* c1w  = (const float*)d_in[2];
  // d_in[3] conv1_b: cancels in BN
  const float* bn1g = (const float*)d_in[4];
  const float* bn1b = (const float*)d_in[5];
  const float* c2w  = (const float*)d_in[6];
  // d_in[7] conv2_b: cancels in BN
  const float* bn2g = (const float*)d_in[8];
  const float* bn2b = (const float*)d_in[9];
  const float* Rw   = (const float*)d_in[10];
  const float* Rb   = (const float*)d_in[11];
  const float* Qw   = (const float*)d_in[12];
  const float* Qb   = (const float*)d_in[13];
  const float* Ow   = (const float*)d_in[14];
  const float* Ob   = (const float*)d_in[15];
  const float* f1w  = (const float*)d_in[16];
  const float* f1b  = (const float*)d_in[17];
  const float* f2w  = (const float*)d_in[18];
  const float* f2b  = (const float*)d_in[19];
  float* outp = (float*)d_out;

  // workspace layout (bytes); total ~60 MB
  char* wsb = (char*)d_ws;
  unsigned short* pool1s = (unsigned short*)wsb;                // 33,554,432 B
  unsigned short* psel2  = (unsigned short*)(wsb + 33554432);   //  8,388,608 B
  float* part1  = (float*)(wsb + 41943040);                     // 524,288 B
  float* part2  = part1 + 131072;                               // 524,288 B
  float* bn1    = part2 + 131072;                               // 512 B
  float* bn2    = bn1 + 128;                                    // 512 B
  float* preQ   = bn2 + 128;                                    // 409,600 B
  unsigned short* wB1 = (unsigned short*)(preQ + 102400);       // 12,288 B
  unsigned short* wB2 = wB1 + 6144;                             // 73,728 B
  unsigned short* qB  = wB2 + 36864;                            // 917,504 B
  float* pqpart = (float*)(qB + 458752);                        // 7,340,032 B

  pack_all<<<1960, 256, 0, stream>>>(c1w, c2w, Qw, wB1, wB2, qB);
  conv1_mfma<<<1024, 256, 0, stream>>>(x1, x2, wB1, bn1g, part1, pool1s);
  bn_finalize<<<64, 256, 0, stream>>>(part1, bn1g, bn1b, 1.f/1048576.f, bn1);
  conv2_mfma<<<1024, 256, 0, stream>>>(pool1s, bn1, bn2g, wB2, part2, psel2);
  bn_finalize<<<64, 256, 0, stream>>>(part2, bn2g, bn2b, 1.f/262144.f, bn2);
  preq_mfma<<<dim3(16,16), 256, 0, stream>>>(psel2, bn2, qB, pqpart);
  preq_reduce<<<400, 256, 0, stream>>>(pqpart, Qb, preQ);
  rnn_head<<<16, 512, 0, stream>>>(preQ, Rw, Rb, Qw, Ow, Ob, f1w, f1b, f2w, f2b, outp);
}